// Round 3
// baseline (25831.018 us; speedup 1.0000x reference)
//
#include <hip/hip_runtime.h>
#include <hip/hip_bf16.h>

#define FDIM 200
#define BB   128
#define LL   256
#define NN   8
#define BL   (BB*LL)
#define AOUTD 39
#define BOUTD 10

// ---------- dtype helpers (runtime bf16-vs-f32 mode) ----------
__device__ __forceinline__ float bflo(unsigned int q){
  union { unsigned int i; float f; } v; v.i = q << 16; return v.f;
}
__device__ __forceinline__ float bfhi(unsigned int q){
  union { unsigned int i; float f; } v; v.i = q & 0xffff0000u; return v.f;
}
__device__ __forceinline__ float bf2f(unsigned short u){
  union { unsigned int i; float f; } v; v.i = ((unsigned int)u) << 16; return v.f;
}
__device__ __forceinline__ unsigned short f2bf(float f){
  unsigned int x = __float_as_uint(f);
  x += 0x7fffu + ((x >> 16) & 1u);   // RNE
  return (unsigned short)(x >> 16);
}
__device__ __forceinline__ float ldf(const void* p, size_t i, bool bf){
  return bf ? bf2f(((const unsigned short*)p)[i]) : ((const float*)p)[i];
}
__device__ __forceinline__ void stf(void* p, size_t i, float v, bool bf){
  if (bf) ((unsigned short*)p)[i] = f2bf(v);
  else    ((float*)p)[i] = v;
}
// dot of a 200-long row (element offset `off`, 8-elem aligned) with f32 LDS x[200]
__device__ __forceinline__ float dotF(const void* wp, size_t off, const float* x, bool bf){
  float acc = 0.f;
  if (bf){
    const uint4* p = (const uint4*)((const unsigned short*)wp + off);
#pragma unroll
    for (int c = 0; c < FDIM/8; ++c){
      uint4 q = p[c];
      const float* xb = x + c*8;
      acc += bflo(q.x)*xb[0]; acc += bfhi(q.x)*xb[1];
      acc += bflo(q.y)*xb[2]; acc += bfhi(q.y)*xb[3];
      acc += bflo(q.z)*xb[4]; acc += bfhi(q.z)*xb[5];
      acc += bflo(q.w)*xb[6]; acc += bfhi(q.w)*xb[7];
    }
  } else {
    const float4* p = (const float4*)((const float*)wp + off);
#pragma unroll
    for (int c = 0; c < FDIM/4; ++c){
      float4 q = p[c];
      const float* xb = x + c*4;
      acc += q.x*xb[0]; acc += q.y*xb[1]; acc += q.z*xb[2]; acc += q.w*xb[3];
    }
  }
  return acc;
}
__device__ __forceinline__ float sigm(float x){ return 1.f/(1.f+__expf(-x)); }
__device__ __forceinline__ float tanh_(float x){
  float cx = fminf(fmaxf(x, -15.f), 15.f);
  float e = __expf(2.f*cx);
  return (e - 1.f)/(e + 1.f);
}
__device__ __forceinline__ float elu_(float x){ return x > 0.f ? x : __expf(x) - 1.f; }

// ---------- dtype probe: atom_mask is all 1.0 ----------
__global__ void k_probe(const unsigned int* __restrict__ amask, int* __restrict__ mode){
  if (blockIdx.x == 0 && threadIdx.x == 0)
    *mode = (amask[0] == 0x3F803F80u) ? 1 : 0;   // packed bf16 {1.0,1.0} vs f32 1.0
}

// ---------- pre_mol[b,f] = mol_align_b[f] + dot(mol[b], mol_align_w[f, :F]) ----------
__global__ __launch_bounds__(256) void k_premol(float* __restrict__ pre,
    const void* __restrict__ molf, const void* __restrict__ maw,
    const void* __restrict__ mab, const int* __restrict__ mode){
  const bool bf = (*mode != 0);
  int b = blockIdx.x, t = threadIdx.x;
  __shared__ float mf[FDIM];
  for (int f = t; f < FDIM; f += 256) mf[f] = ldf(molf, (size_t)b*FDIM+f, bf);
  __syncthreads();
  for (int f = t; f < FDIM; f += 256)
    pre[b*FDIM+f] = ldf(mab, f, bf) + dotF(maw, (size_t)f*2*FDIM, mf, bf);
}

// ---------- mw softmax over L + git init ----------
__global__ __launch_bounds__(LL) void k_git(float* __restrict__ git,
    const void* __restrict__ molf, const void* __restrict__ actf,
    const int* __restrict__ mode){
  const bool bf = (*mode != 0);
  int b = blockIdx.x, l = threadIdx.x;
  __shared__ float mf[FDIM];
  __shared__ float red[LL];
  __shared__ float mw[LL];
  __shared__ float actl[FDIM];  // unused pad avoidance
  (void)actl;
  for (int f = l; f < FDIM; f += LL) mf[f] = ldf(molf, (size_t)b*FDIM+f, bf);
  __syncthreads();
  float d = dotF(actf, ((size_t)b*LL + l)*FDIM, mf, bf);
  red[l] = d; __syncthreads();
  for (int s = 128; s > 0; s >>= 1){ if (l < s) red[l] = fmaxf(red[l], red[l+s]); __syncthreads(); }
  float m = red[0]; __syncthreads();
  float e = __expf(d - m);
  red[l] = e; __syncthreads();
  for (int s = 128; s > 0; s >>= 1){ if (l < s) red[l] += red[l+s]; __syncthreads(); }
  mw[l] = e / red[0];
  __syncthreads();
  size_t base = (size_t)b*LL*FDIM;
  float* gout = git + base;
  for (int i = l; i < LL*FDIM; i += LL){
    int ll = i / FDIM, f = i - ll*FDIM;
    gout[i] = mw[ll]*mf[f] + ldf(actf, base + i, bf);
  }
}

// ---------- one mol-GRU step (in place on git) ----------
__global__ __launch_bounds__(256) void k_molgru(float* __restrict__ git,
    const float* __restrict__ pre, const void* __restrict__ maw,
    const void* __restrict__ wih, const void* __restrict__ whh,
    const void* __restrict__ bih, const void* __restrict__ bhh,
    const int* __restrict__ mode){
  const bool bf = (*mode != 0);
  int atom = blockIdx.x, b = atom / LL, t = threadIdx.x;
  __shared__ float h[FDIM], ctx[FDIM], gi[3*FDIM], gh[3*FDIM];
  for (int f = t; f < FDIM; f += 256) h[f] = git[(size_t)atom*FDIM + f];
  __syncthreads();
  for (int f = t; f < FDIM; f += 256){
    float s = pre[b*FDIM + f] + dotF(maw, (size_t)f*2*FDIM + FDIM, h, bf);
    ctx[f] = elu_(s);
  }
  __syncthreads();
  for (int j = t; j < 3*FDIM; j += 256){
    gi[j] = ldf(bih, j, bf) + dotF(wih, (size_t)j*FDIM, ctx, bf);
    gh[j] = ldf(bhh, j, bf) + dotF(whh, (size_t)j*FDIM, h, bf);
  }
  __syncthreads();
  for (int f = t; f < FDIM; f += 256){
    float r = sigm(gi[f] + gh[f]);
    float z = sigm(gi[FDIM+f] + gh[FDIM+f]);
    float n = tanh_(gi[2*FDIM+f] + r*gh[2*FDIM+f]);
    git[(size_t)atom*FDIM + f] = (1.f - z)*n + z*h[f];
  }
}

__global__ void k_relu(float* __restrict__ x, int n){
  int i = blockIdx.x*blockDim.x + threadIdx.x;
  if (i < n) x[i] = fmaxf(x[i], 0.f);
}

// ---------- one attention+GRU round: act_in -> act_out ----------
__global__ __launch_bounds__(256) void k_round(
    const float* __restrict__ act_in, float* __restrict__ act_out,
    const int* __restrict__ adeg,
    const void* __restrict__ alw, const void* __restrict__ alb,
    const void* __restrict__ atw, const void* __restrict__ atb,
    const void* __restrict__ wih, const void* __restrict__ whh,
    const void* __restrict__ bih, const void* __restrict__ bhh,
    int rd, const int* __restrict__ mode){
  const bool bf = (*mode != 0);
  const size_t oal = (size_t)rd*FDIM*2*FDIM, oalb = (size_t)rd*FDIM;
  const size_t oat = (size_t)rd*FDIM*FDIM,   oatb = (size_t)rd*FDIM;
  const size_t ogw = (size_t)rd*3*FDIM*FDIM, ogb  = (size_t)rd*3*FDIM;
  int atom = blockIdx.x, b = atom / LL, t = threadIdx.x;
  __shared__ float self[FDIM];
  __shared__ float nbr[NN][FDIM];
  __shared__ float selfp[FDIM];
  __shared__ float score[NN][FDIM];
  __shared__ float ntt[NN][FDIM];
  __shared__ float ctx[FDIM];
  __shared__ float gi[3*FDIM], gh[3*FDIM];
  __shared__ int   nidx[NN];
  __shared__ float nmadd[NN], nmmul[NN];

  if (t < NN){
    int idx = adeg[(size_t)atom*NN + t];
    nidx[t] = idx;
    bool pad = (idx == LL-1);
    nmadd[t] = pad ? -9e8f : 0.f;
    nmmul[t] = pad ? 0.f : 1.f;
  }
  for (int f = t; f < FDIM; f += 256) self[f] = act_in[(size_t)atom*FDIM + f];
  __syncthreads();
  for (int i = t; i < NN*FDIM; i += 256){
    int n = i / FDIM, f = i - n*FDIM;
    nbr[n][f] = act_in[((size_t)b*LL + nidx[n])*FDIM + f];
  }
  for (int f = t; f < FDIM; f += 256)
    selfp[f] = ldf(alb, oalb + f, bf) + dotF(alw, oal + (size_t)f*2*FDIM, self, bf);
  __syncthreads();
  for (int i = t; i < NN*FDIM; i += 256){
    int n = i / FDIM, f = i - n*FDIM;
    float s = selfp[f] + dotF(alw, oal + (size_t)f*2*FDIM + FDIM, nbr[n], bf);
    s = s > 0.f ? s : 0.01f*s;
    score[n][f] = s + nmadd[n];
    ntt[n][f] = ldf(atb, oatb + f, bf) + dotF(atw, oat + (size_t)f*FDIM, nbr[n], bf);
  }
  __syncthreads();
  for (int f = t; f < FDIM; f += 256){
    float m = -1e30f;
    #pragma unroll
    for (int n = 0; n < NN; n++) m = fmaxf(m, score[n][f]);
    float e[NN]; float sum = 0.f;
    #pragma unroll
    for (int n = 0; n < NN; n++){ e[n] = __expf(score[n][f] - m); sum += e[n]; }
    float inv = 1.f / sum, acc = 0.f;
    #pragma unroll
    for (int n = 0; n < NN; n++) acc += e[n]*inv*nmmul[n]*ntt[n][f];
    ctx[f] = elu_(acc);
  }
  __syncthreads();
  for (int j = t; j < 3*FDIM; j += 256){
    gi[j] = ldf(bih, ogb + j, bf) + dotF(wih, ogw + (size_t)j*FDIM, ctx, bf);
    gh[j] = ldf(bhh, ogb + j, bf) + dotF(whh, ogw + (size_t)j*FDIM, self, bf);
  }
  __syncthreads();
  for (int f = t; f < FDIM; f += 256){
    float r = sigm(gi[f] + gh[f]);
    float z = sigm(gi[FDIM+f] + gh[FDIM+f]);
    float n = tanh_(gi[2*FDIM+f] + r*gh[2*FDIM+f]);
    float hn = (1.f - z)*n + z*self[f];
    act_out[(size_t)atom*FDIM + f] = fmaxf(hn, 0.f);
  }
}

// ---------- atom decode ----------
__global__ __launch_bounds__(64) void k_atomdec(const float* __restrict__ act,
    const void* __restrict__ afw, const void* __restrict__ afb,
    void* __restrict__ out, const int* __restrict__ mode){
  const bool bf = (*mode != 0);
  int atom = blockIdx.x, t = threadIdx.x;
  __shared__ float self[FDIM];
  __shared__ float al[AOUTD];
  __shared__ float segm[4], segs[4];
  const int lo[4] = {0,16,24,31}, hi[4] = {16,22,30,36};
  for (int f = t; f < FDIM; f += 64) self[f] = act[(size_t)atom*FDIM + f];
  __syncthreads();
  if (t < AOUTD) al[t] = ldf(afb, t, bf) + dotF(afw, (size_t)t*FDIM, self, bf);
  __syncthreads();
  if (t < 4){
    float m = -1e30f;
    for (int k = lo[t]; k < hi[t]; k++) m = fmaxf(m, al[k]);
    float s = 0.f;
    for (int k = lo[t]; k < hi[t]; k++) s += __expf(al[k]-m);
    segm[t] = m; segs[t] = s;
  }
  __syncthreads();
  if (t < AOUTD){
    float v = 0.f;
    #pragma unroll
    for (int g = 0; g < 4; g++)
      if (t >= lo[g] && t < hi[g]) v += __expf(al[t]-segm[g])/segs[g];
    if (t == 24) v += fmaxf(al[24], 0.f);
    if (t == 30 || t == 36 || t == 37 || t == 38) v += sigm(al[t]);
    stf(out, (size_t)atom*AOUTD + t, v, bf);
  }
}

// ---------- bond decode ----------
__global__ __launch_bounds__(64) void k_bonddec(const float* __restrict__ act,
    const int* __restrict__ adeg,
    const void* __restrict__ bfw, const void* __restrict__ bfb,
    void* __restrict__ out, const int* __restrict__ mode){
  const bool bf = (*mode != 0);
  const size_t obase = (size_t)BL*AOUTD;   // bond output follows atom output
  int atom = blockIdx.x, b = atom / LL, t = threadIdx.x;
  __shared__ float self[FDIM];
  __shared__ float nbr[NN][FDIM];
  __shared__ int nidx[NN];
  __shared__ float blv[NN][BOUTD];
  if (t < NN) nidx[t] = adeg[(size_t)atom*NN + t];
  for (int f = t; f < FDIM; f += 64) self[f] = act[(size_t)atom*FDIM + f];
  __syncthreads();
  for (int i = t; i < NN*FDIM; i += 64){
    int n = i / FDIM, f = i - n*FDIM;
    nbr[n][f] = act[((size_t)b*LL + nidx[n])*FDIM + f];
  }
  __syncthreads();
  for (int i = t; i < NN*BOUTD; i += 64){
    int n = i / BOUTD, o = i - n*BOUTD;
    blv[n][o] = ldf(bfb, o, bf)
              + dotF(bfw, (size_t)o*2*FDIM, self, bf)
              + dotF(bfw, (size_t)o*2*FDIM + FDIM, nbr[n], bf);
  }
  __syncthreads();
  if (t < NN){
    float v[BOUTD];
    float m0 = fmaxf(fmaxf(blv[t][0],blv[t][1]), fmaxf(blv[t][2],blv[t][3]));
    float e0[4], s0 = 0.f;
    #pragma unroll
    for (int j = 0; j < 4; j++){ e0[j] = __expf(blv[t][j]-m0); s0 += e0[j]; }
    float m1 = fmaxf(fmaxf(blv[t][6],blv[t][7]), fmaxf(blv[t][8],blv[t][9]));
    float e1[4], s1 = 0.f;
    #pragma unroll
    for (int j = 0; j < 4; j++){ e1[j] = __expf(blv[t][6+j]-m1); s1 += e1[j]; }
    #pragma unroll
    for (int j = 0; j < 4; j++) v[j] = e0[j]/s0;
    v[4] = sigm(blv[t][4]); v[5] = sigm(blv[t][5]);
    #pragma unroll
    for (int j = 0; j < 4; j++) v[6+j] = e1[j]/s1;
    size_t op = obase + ((size_t)atom*NN + t)*BOUTD;
    #pragma unroll
    for (int j = 0; j < BOUTD; j++) stf(out, op + j, v[j], bf);
  }
}

extern "C" void kernel_launch(void* const* d_in, const int* in_sizes, int n_in,
                              void* d_out, int out_size, void* d_ws, size_t ws_size,
                              hipStream_t stream) {
  const int* adeg = (const int*)d_in[2];
  const void* amask = d_in[4];
  const void* molf = d_in[5];
  const void* actf = d_in[6];
  const void* afw = d_in[7];  const void* afb = d_in[8];
  const void* bfw = d_in[9];  const void* bfb = d_in[10];
  const void* alw = d_in[11]; const void* alb = d_in[12];
  const void* atw = d_in[13]; const void* atb = d_in[14];
  const void* gwih = d_in[15]; const void* gwhh = d_in[16];
  const void* gbih = d_in[17]; const void* gbhh = d_in[18];
  const void* maw = d_in[19]; const void* mab = d_in[20];
  const void* mwih = d_in[21]; const void* mwhh = d_in[22];
  const void* mbih = d_in[23]; const void* mbhh = d_in[24];

  float* bufA = (float*)d_ws;                       // [BL,F]
  float* bufB = bufA + (size_t)BL*FDIM;             // [BL,F]
  float* pre  = bufB + (size_t)BL*FDIM;             // [B,F]
  int*  mode  = (int*)(pre + (size_t)BB*FDIM);

  k_probe<<<1, 64, 0, stream>>>((const unsigned int*)amask, mode);
  k_premol<<<BB, 256, 0, stream>>>(pre, molf, maw, mab, mode);
  k_git<<<BB, LL, 0, stream>>>(bufA, molf, actf, mode);
  for (int tstep = 0; tstep < 2; tstep++)
    k_molgru<<<BL, 256, 0, stream>>>(bufA, pre, maw, mwih, mwhh, mbih, mbhh, mode);
  k_relu<<<(BL*FDIM + 255)/256, 256, 0, stream>>>(bufA, BL*FDIM);

  // round 0: A -> B ; round 1: B -> A
  k_round<<<BL, 256, 0, stream>>>(bufA, bufB, adeg,
      alw, alb, atw, atb, gwih, gwhh, gbih, gbhh, 0, mode);
  k_round<<<BL, 256, 0, stream>>>(bufB, bufA, adeg,
      alw, alb, atw, atb, gwih, gwhh, gbih, gbhh, 1, mode);

  k_atomdec<<<BL, 64, 0, stream>>>(bufA, afw, afb, d_out, mode);
  k_bonddec<<<BL, 64, 0, stream>>>(bufA, adeg, bfw, bfb, d_out, mode);
}

// Round 4
// 2306.299 us; speedup vs baseline: 11.2002x; 11.2002x over previous
//
#include <hip/hip_runtime.h>
#include <hip/hip_bf16.h>

#define FDIM 200
#define BB   128
#define LL   256
#define NN   8
#define BL   (BB*LL)
#define AOUTD 39
#define BOUTD 10
#define CH   8192          // atoms per chunk (32 molecules)
#define NCH  (BL/CH)       // 4 chunks
#define KP   224           // K padded to 7*32
#define LDA  232           // LDS row stride (bf16 elems); 464B -> 2-way-free banking

typedef short v8s __attribute__((ext_vector_type(8)));
typedef float v4f __attribute__((ext_vector_type(4)));

// ---------- dtype helpers (runtime bf16-vs-f32 mode for INPUT tensors) ----------
__device__ __forceinline__ float bf2f(unsigned short u){
  union { unsigned int i; float f; } v; v.i = ((unsigned int)u) << 16; return v.f;
}
__device__ __forceinline__ unsigned short f2bf(float f){
  unsigned int x = __float_as_uint(f);
  x += 0x7fffu + ((x >> 16) & 1u);   // RNE
  return (unsigned short)(x >> 16);
}
__device__ __forceinline__ float ldf(const void* p, size_t i, bool bf){
  return bf ? bf2f(((const unsigned short*)p)[i]) : ((const float*)p)[i];
}
__device__ __forceinline__ void stf(void* p, size_t i, float v, bool bf){
  if (bf) ((unsigned short*)p)[i] = f2bf(v);
  else    ((float*)p)[i] = v;
}
__device__ __forceinline__ float bflo(unsigned int q){
  union { unsigned int i; float f; } v; v.i = q << 16; return v.f;
}
__device__ __forceinline__ float bfhi(unsigned int q){
  union { unsigned int i; float f; } v; v.i = q & 0xffff0000u; return v.f;
}
// dot of a 200-long input row (element offset off) with f32 LDS x[200]
__device__ __forceinline__ float dotF(const void* wp, size_t off, const float* x, bool bf){
  float a0=0.f,a1=0.f,a2=0.f,a3=0.f;
  if (bf){
    const uint4* p = (const uint4*)((const unsigned short*)wp + off);
#pragma unroll
    for (int c = 0; c < FDIM/8; ++c){
      uint4 q = p[c];
      const float* xb = x + c*8;
      a0 += bflo(q.x)*xb[0]; a1 += bfhi(q.x)*xb[1];
      a2 += bflo(q.y)*xb[2]; a3 += bfhi(q.y)*xb[3];
      a0 += bflo(q.z)*xb[4]; a1 += bfhi(q.z)*xb[5];
      a2 += bflo(q.w)*xb[6]; a3 += bfhi(q.w)*xb[7];
    }
  } else {
    const float4* p = (const float4*)((const float*)wp + off);
#pragma unroll
    for (int c = 0; c < FDIM/4; ++c){
      float4 q = p[c];
      const float* xb = x + c*4;
      a0 += q.x*xb[0]; a1 += q.y*xb[1]; a2 += q.z*xb[2]; a3 += q.w*xb[3];
    }
  }
  return (a0+a1)+(a2+a3);
}
__device__ __forceinline__ float sigm(float x){ return 1.f/(1.f+__expf(-x)); }
__device__ __forceinline__ float tanh_(float x){
  float cx = fminf(fmaxf(x, -15.f), 15.f);
  float e = __expf(2.f*cx);
  return (e - 1.f)/(e + 1.f);
}
__device__ __forceinline__ float elu_(float x){ return x > 0.f ? x : __expf(x) - 1.f; }

// ---------- dtype probe: atom_mask is all 1.0 ----------
__global__ void k_probe(const unsigned int* __restrict__ amask, int* __restrict__ mode){
  if (blockIdx.x == 0 && threadIdx.x == 0)
    *mode = (amask[0] == 0x3F803F80u) ? 1 : 0;
}

// ---------- GEMM: C[m,n] = sum_k A[m,k] * W[wbase + n*wstride + k], K=200 ----------
// A: bf16 [rows,200] row-major. C: bf16 (or f32) [rows, ldc].
// block = 256 thr = 4 waves; tile M=64 (16 per wave), N=16; grid (ceil(Nout/16), rows/64)
__global__ __launch_bounds__(256) void k_gemm(
    const unsigned short* __restrict__ A,
    const void* __restrict__ W, unsigned long long wbase, int wstride,
    void* __restrict__ C, int ldc, int Nout, int c_f32,
    const int* __restrict__ mode)
{
  const bool bf = (*mode != 0);
  __shared__ unsigned short As[64*LDA];
  __shared__ unsigned short Ws[16*LDA];
  int t = threadIdx.x;
  int mbase = blockIdx.y * 64;
  int nbase = blockIdx.x * 16;
  // stage A: 64 rows x 200 bf16 = 25 uint4 per row (rows contiguous in global)
  {
    const uint4* Ag = (const uint4*)(A + (size_t)mbase*FDIM);
    for (int i = t; i < 64*25; i += 256){
      int r = i/25, c = i - r*25;
      uint4 q = Ag[(size_t)r*25 + c];
      *(uint4*)(As + r*LDA + c*8) = q;
    }
    for (int i = t; i < 64*(LDA-FDIM); i += 256){
      int r = i/(LDA-FDIM), c = FDIM + (i - r*(LDA-FDIM));
      As[r*LDA + c] = 0;
    }
  }
  // stage W tile: 16 rows x LDA (zero-padded k>=200 and n>=Nout)
  for (int i = t; i < 16*LDA; i += 256){
    int r = i/LDA, c = i - r*LDA;
    int n = nbase + r;
    unsigned short v = 0;
    if (c < FDIM && n < Nout){
      size_t off = wbase + (size_t)n*wstride + c;
      v = bf ? ((const unsigned short*)W)[off] : f2bf(((const float*)W)[off]);
    }
    Ws[r*LDA + c] = v;
  }
  __syncthreads();
  int wave = t >> 6, lane = t & 63;
  int am   = wave*16 + (lane & 15);
  int koct = (lane >> 4) * 8;
  v4f acc = {0.f,0.f,0.f,0.f};
#pragma unroll
  for (int ks = 0; ks < KP/32; ks++){
    v8s a = *(const v8s*)(As + am*LDA + ks*32 + koct);
    v8s b = *(const v8s*)(Ws + (lane & 15)*LDA + ks*32 + koct);
    acc = __builtin_amdgcn_mfma_f32_16x16x32_bf16(a, b, acc, 0, 0, 0);
  }
  int col = nbase + (lane & 15);
  if (col < Nout){
    int r0 = mbase + wave*16 + (lane >> 4)*4;
    if (c_f32){
      float* Cf = (float*)C;
#pragma unroll
      for (int j = 0; j < 4; j++) Cf[(size_t)(r0+j)*ldc + col] = acc[j];
    } else {
      unsigned short* Ch = (unsigned short*)C;
#pragma unroll
      for (int j = 0; j < 4; j++) Ch[(size_t)(r0+j)*ldc + col] = f2bf(acc[j]);
    }
  }
}

// ---------- pre_mol[b,f] = dot(mol[b], maw[f, :F]) (mab==0 but add anyway) ----------
__global__ __launch_bounds__(256) void k_premol(float* __restrict__ pre,
    const void* __restrict__ molf, const void* __restrict__ maw,
    const void* __restrict__ mab, const int* __restrict__ mode){
  const bool bf = (*mode != 0);
  int b = blockIdx.x, t = threadIdx.x;
  __shared__ float mf[FDIM];
  for (int f = t; f < FDIM; f += 256) mf[f] = ldf(molf, (size_t)b*FDIM+f, bf);
  __syncthreads();
  for (int f = t; f < FDIM; f += 256)
    pre[b*FDIM+f] = ldf(mab, f, bf) + dotF(maw, (size_t)f*2*FDIM, mf, bf);
}

// ---------- mw softmax over L + git init (act <- bf16) ----------
__global__ __launch_bounds__(LL) void k_git(unsigned short* __restrict__ act,
    const void* __restrict__ molf, const void* __restrict__ actf,
    const int* __restrict__ mode){
  const bool bf = (*mode != 0);
  int b = blockIdx.x, l = threadIdx.x;
  __shared__ float mf[FDIM];
  __shared__ float red[LL];
  __shared__ float mw[LL];
  for (int f = l; f < FDIM; f += LL) mf[f] = ldf(molf, (size_t)b*FDIM+f, bf);
  __syncthreads();
  float d = dotF(actf, ((size_t)b*LL + l)*FDIM, mf, bf);
  red[l] = d; __syncthreads();
  for (int s = 128; s > 0; s >>= 1){ if (l < s) red[l] = fmaxf(red[l], red[l+s]); __syncthreads(); }
  float m = red[0]; __syncthreads();
  float e = __expf(d - m);
  red[l] = e; __syncthreads();
  for (int s = 128; s > 0; s >>= 1){ if (l < s) red[l] += red[l+s]; __syncthreads(); }
  mw[l] = e / red[0];
  __syncthreads();
  size_t base = (size_t)b*LL*FDIM;
  for (int i = l; i < LL*FDIM; i += LL){
    int ll = i / FDIM, f = i - ll*FDIM;
    act[base + i] = f2bf(mw[ll]*mf[f] + ldf(actf, base + i, bf));
  }
}

// ---------- mol ctx: T1 <- elu(pre[b] + T1) (in place) ----------
__global__ __launch_bounds__(256) void k_ctx_mol(unsigned short* __restrict__ T1,
    const float* __restrict__ pre, int base){
  int a = blockIdx.x, t = threadIdx.x;
  if (t < FDIM){
    int b = (base + a) / LL;
    float v = pre[b*FDIM + t] + bf2f(T1[(size_t)a*FDIM + t]);
    T1[(size_t)a*FDIM + t] = f2bf(elu_(v));
  }
}

// ---------- GRU elementwise: act <- gru(gi,gh,act) (in place), opt relu ----------
__global__ __launch_bounds__(256) void k_gru_ew(unsigned short* __restrict__ act,
    const unsigned short* __restrict__ G1, const unsigned short* __restrict__ G2,
    const void* __restrict__ bih, const void* __restrict__ bhh,
    unsigned long long ob, int dorelu, const int* __restrict__ mode){
  const bool bf = (*mode != 0);
  int a = blockIdx.x, t = threadIdx.x;
  if (t < FDIM){
    size_t g = (size_t)a*3*FDIM;
    float gir = bf2f(G1[g + t])        + ldf(bih, ob + t, bf);
    float giz = bf2f(G1[g + FDIM + t]) + ldf(bih, ob + FDIM + t, bf);
    float gin = bf2f(G1[g + 2*FDIM+t]) + ldf(bih, ob + 2*FDIM + t, bf);
    float ghr = bf2f(G2[g + t])        + ldf(bhh, ob + t, bf);
    float ghz = bf2f(G2[g + FDIM + t]) + ldf(bhh, ob + FDIM + t, bf);
    float ghn = bf2f(G2[g + 2*FDIM+t]) + ldf(bhh, ob + 2*FDIM + t, bf);
    float r = sigm(gir + ghr);
    float z = sigm(giz + ghz);
    float n = tanh_(gin + r*ghn);
    float h = bf2f(act[(size_t)a*FDIM + t]);
    float hn = (1.f - z)*n + z*h;
    if (dorelu) hn = fmaxf(hn, 0.f);
    act[(size_t)a*FDIM + t] = f2bf(hn);
  }
}

// ---------- attention elementwise: T1(=S) -> ctx, using P=T2, Q=T3 gathers ----------
__global__ __launch_bounds__(256) void k_attn_ew(unsigned short* __restrict__ T1,
    const unsigned short* __restrict__ T2, const unsigned short* __restrict__ T3,
    const int* __restrict__ adeg,
    const void* __restrict__ alb, const void* __restrict__ atb,
    unsigned long long boff, int base, const int* __restrict__ mode){
  const bool bf = (*mode != 0);
  int a = blockIdx.x, t = threadIdx.x;
  __shared__ int   nidx[NN];
  __shared__ float nmadd[NN], nmmul[NN];
  if (t < NN){
    int idx = adeg[((size_t)(base + a))*NN + t];
    nidx[t] = (a / LL)*LL + idx;            // chunk-local neighbor row
    bool pad = (idx == LL-1);
    nmadd[t] = pad ? -9e8f : 0.f;
    nmmul[t] = pad ? 0.f : 1.f;
  }
  __syncthreads();
  if (t < FDIM){
    float s0 = bf2f(T1[(size_t)a*FDIM + t]) + ldf(alb, boff + t, bf);
    float sc[NN];
#pragma unroll
    for (int n = 0; n < NN; n++){
      float s = s0 + bf2f(T2[(size_t)nidx[n]*FDIM + t]);
      s = s > 0.f ? s : 0.01f*s;
      sc[n] = s + nmadd[n];
    }
    float m = -1e30f;
#pragma unroll
    for (int n = 0; n < NN; n++) m = fmaxf(m, sc[n]);
    float e[NN]; float sum = 0.f;
#pragma unroll
    for (int n = 0; n < NN; n++){ e[n] = __expf(sc[n] - m); sum += e[n]; }
    float inv = 1.f/sum, acc = 0.f;
#pragma unroll
    for (int n = 0; n < NN; n++){
      float nt = bf2f(T3[(size_t)nidx[n]*FDIM + t]) + ldf(atb, boff + t, bf);
      acc += e[n]*inv*nmmul[n]*nt;
    }
    T1[(size_t)a*FDIM + t] = f2bf(elu_(acc));
  }
}

// ---------- atom decode ew: AL f32 [CH,40] in G1f ----------
__global__ __launch_bounds__(64) void k_atom_ew(const float* __restrict__ ALf,
    const void* __restrict__ afb, void* __restrict__ out, int base,
    const int* __restrict__ mode){
  const bool bf = (*mode != 0);
  int a = blockIdx.x, t = threadIdx.x;
  __shared__ float al[AOUTD];
  __shared__ float segm[4], segs[4];
  const int lo[4] = {0,16,24,31}, hi[4] = {16,22,30,36};
  if (t < AOUTD) al[t] = ALf[(size_t)a*40 + t] + ldf(afb, t, bf);
  __syncthreads();
  if (t < 4){
    float m = -1e30f;
    for (int k = lo[t]; k < hi[t]; k++) m = fmaxf(m, al[k]);
    float s = 0.f;
    for (int k = lo[t]; k < hi[t]; k++) s += __expf(al[k]-m);
    segm[t] = m; segs[t] = s;
  }
  __syncthreads();
  if (t < AOUTD){
    float v = 0.f;
#pragma unroll
    for (int g = 0; g < 4; g++)
      if (t >= lo[g] && t < hi[g]) v += __expf(al[t]-segm[g])/segs[g];
    if (t == 24) v += fmaxf(al[24], 0.f);
    if (t == 30 || t == 36 || t == 37 || t == 38) v += sigm(al[t]);
    stf(out, (size_t)(base + a)*AOUTD + t, v, bf);
  }
}

// ---------- bond decode ew: U=T2 [CH,16], V=T3 [CH,16] ----------
__global__ __launch_bounds__(64) void k_bond_ew(const unsigned short* __restrict__ U,
    const unsigned short* __restrict__ V, const int* __restrict__ adeg,
    const void* __restrict__ bfb, void* __restrict__ out, int base,
    const int* __restrict__ mode){
  const bool bf = (*mode != 0);
  const size_t obase = (size_t)BL*AOUTD;
  int a = blockIdx.x, t = threadIdx.x;
  if (t < NN){
    int idx = adeg[((size_t)(base + a))*NN + t];
    int vr = (a / LL)*LL + idx;
    float bl[BOUTD];
#pragma unroll
    for (int o = 0; o < BOUTD; o++)
      bl[o] = bf2f(U[(size_t)a*16 + o]) + bf2f(V[(size_t)vr*16 + o]) + ldf(bfb, o, bf);
    float v[BOUTD];
    float m0 = fmaxf(fmaxf(bl[0],bl[1]), fmaxf(bl[2],bl[3]));
    float e0[4], s0 = 0.f;
#pragma unroll
    for (int j = 0; j < 4; j++){ e0[j] = __expf(bl[j]-m0); s0 += e0[j]; }
    float m1 = fmaxf(fmaxf(bl[6],bl[7]), fmaxf(bl[8],bl[9]));
    float e1[4], s1 = 0.f;
#pragma unroll
    for (int j = 0; j < 4; j++){ e1[j] = __expf(bl[6+j]-m1); s1 += e1[j]; }
#pragma unroll
    for (int j = 0; j < 4; j++) v[j] = e0[j]/s0;
    v[4] = sigm(bl[4]); v[5] = sigm(bl[5]);
#pragma unroll
    for (int j = 0; j < 4; j++) v[6+j] = e1[j]/s1;
    size_t op = obase + ((size_t)(base + a)*NN + t)*BOUTD;
#pragma unroll
    for (int j = 0; j < BOUTD; j++) stf(out, op + j, v[j], bf);
  }
}

extern "C" void kernel_launch(void* const* d_in, const int* in_sizes, int n_in,
                              void* d_out, int out_size, void* d_ws, size_t ws_size,
                              hipStream_t stream) {
  const int* adeg = (const int*)d_in[2];
  const void* amask = d_in[4];
  const void* molf = d_in[5];
  const void* actf = d_in[6];
  const void* afw = d_in[7];  const void* afb = d_in[8];
  const void* bfw = d_in[9];  const void* bfb = d_in[10];
  const void* alw = d_in[11]; const void* alb = d_in[12];
  const void* atw = d_in[13]; const void* atb = d_in[14];
  const void* gwih = d_in[15]; const void* gwhh = d_in[16];
  const void* gbih = d_in[17]; const void* gbhh = d_in[18];
  const void* maw = d_in[19]; const void* mab = d_in[20];
  const void* mwih = d_in[21]; const void* mwhh = d_in[22];
  const void* mbih = d_in[23]; const void* mbhh = d_in[24];

  // ws layout (bytes): act 13.11M | T1,T2,T3 3.28M each | G1,G2 9.83M each | pre | mode
  char* w = (char*)d_ws;
  unsigned short* act = (unsigned short*)w;                 w += (size_t)BL*FDIM*2;
  unsigned short* T1  = (unsigned short*)w;                 w += (size_t)CH*FDIM*2;
  unsigned short* T2  = (unsigned short*)w;                 w += (size_t)CH*FDIM*2;
  unsigned short* T3  = (unsigned short*)w;                 w += (size_t)CH*FDIM*2;
  unsigned short* G1  = (unsigned short*)w;                 w += (size_t)CH*3*FDIM*2;
  unsigned short* G2  = (unsigned short*)w;                 w += (size_t)CH*3*FDIM*2;
  float* pre = (float*)w;                                   w += (size_t)BB*FDIM*4;
  int* mode = (int*)w;
  float* ALf = (float*)G1;   // decode reuse: [CH,40] f32

  const dim3 g200(13, CH/64), g600(38, CH/64), g48(3, CH/64), g16(1, CH/64);

  k_probe<<<1, 64, 0, stream>>>((const unsigned int*)amask, mode);
  k_premol<<<BB, 256, 0, stream>>>(pre, molf, maw, mab, mode);
  k_git<<<BB, LL, 0, stream>>>(act, molf, actf, mode);

  // ---- mol GRU x2 ----
  for (int ts = 0; ts < 2; ts++){
    for (int c = 0; c < NCH; c++){
      int base = c*CH;
      const unsigned short* Ac = act + (size_t)base*FDIM;
      // raw ctx = act @ maw[:,200:400]^T
      k_gemm<<<g200, 256, 0, stream>>>(Ac, maw, 200ull, 2*FDIM, T1, FDIM, FDIM, 0, mode);
      k_ctx_mol<<<CH, 256, 0, stream>>>(T1, pre, base);
      k_gemm<<<g600, 256, 0, stream>>>(Ac, mwhh, 0ull, FDIM, G2, 3*FDIM, 3*FDIM, 0, mode);
      k_gemm<<<g600, 256, 0, stream>>>(T1, mwih, 0ull, FDIM, G1, 3*FDIM, 3*FDIM, 0, mode);
      k_gru_ew<<<CH, 256, 0, stream>>>(act + (size_t)base*FDIM, G1, G2, mbih, mbhh,
                                       0ull, (ts == 1), mode);
    }
  }

  // ---- 2 attention+GRU rounds ----
  for (int d = 0; d < 2; d++){
    unsigned long long oal = (unsigned long long)d*FDIM*2*FDIM;
    unsigned long long oat = (unsigned long long)d*FDIM*FDIM;
    unsigned long long ogw = (unsigned long long)d*3*FDIM*FDIM;
    unsigned long long ob  = (unsigned long long)d*FDIM;
    unsigned long long ogb = (unsigned long long)d*3*FDIM;
    for (int c = 0; c < NCH; c++){
      int base = c*CH;
      const unsigned short* Ac = act + (size_t)base*FDIM;
      k_gemm<<<g200, 256, 0, stream>>>(Ac, alw, oal,        2*FDIM, T1, FDIM, FDIM, 0, mode); // S
      k_gemm<<<g200, 256, 0, stream>>>(Ac, alw, oal + FDIM, 2*FDIM, T2, FDIM, FDIM, 0, mode); // P
      k_gemm<<<g200, 256, 0, stream>>>(Ac, atw, oat,        FDIM,   T3, FDIM, FDIM, 0, mode); // Q
      k_attn_ew<<<CH, 256, 0, stream>>>(T1, T2, T3, adeg, alb, atb, ob, base, mode);          // T1=ctx
      k_gemm<<<g600, 256, 0, stream>>>(Ac, gwhh, ogw, FDIM, G2, 3*FDIM, 3*FDIM, 0, mode);     // gh
      k_gemm<<<g600, 256, 0, stream>>>(T1, gwih, ogw, FDIM, G1, 3*FDIM, 3*FDIM, 0, mode);     // gi
      k_gru_ew<<<CH, 256, 0, stream>>>(act + (size_t)base*FDIM, G1, G2, gbih, gbhh,
                                       ogb, 1, mode);
    }
  }

  // ---- decode ----
  for (int c = 0; c < NCH; c++){
    int base = c*CH;
    const unsigned short* Ac = act + (size_t)base*FDIM;
    k_gemm<<<g48, 256, 0, stream>>>(Ac, afw, 0ull, FDIM, ALf, 40, AOUTD, 1, mode);
    k_atom_ew<<<CH, 64, 0, stream>>>(ALf, afb, d_out, base, mode);
    k_gemm<<<g16, 256, 0, stream>>>(Ac, bfw, 0ull,         2*FDIM, T2, 16, BOUTD, 0, mode);  // U
    k_gemm<<<g16, 256, 0, stream>>>(Ac, bfw, (unsigned long long)FDIM, 2*FDIM, T3, 16, BOUTD, 0, mode); // V
    k_bond_ew<<<CH, 64, 0, stream>>>(T2, T3, adeg, bfb, d_out, base, mode);
  }
}

// Round 5
// 1004.480 us; speedup vs baseline: 25.7158x; 2.2960x over previous
//
#include <hip/hip_runtime.h>
#include <hip/hip_bf16.h>

#define FDIM 200
#define BB   128
#define LL   256
#define NN   8
#define BL   (BB*LL)
#define AOUTD 39
#define BOUTD 10
#define LDA  232           // LDS row stride (bf16 elems); 464B rows -> only 2-way bank aliasing (free)
#define WREP_ROWS 5064

typedef short v8s __attribute__((ext_vector_type(8)));
typedef float v4f __attribute__((ext_vector_type(4)));

// ---------- dtype helpers (runtime bf16-vs-f32 mode for INPUT tensors) ----------
__device__ __forceinline__ float bf2f(unsigned short u){
  union { unsigned int i; float f; } v; v.i = ((unsigned int)u) << 16; return v.f;
}
__device__ __forceinline__ unsigned short f2bf(float f){
  unsigned int x = __float_as_uint(f);
  x += 0x7fffu + ((x >> 16) & 1u);   // RNE
  return (unsigned short)(x >> 16);
}
__device__ __forceinline__ float ldf(const void* p, size_t i, bool bf){
  return bf ? bf2f(((const unsigned short*)p)[i]) : ((const float*)p)[i];
}
__device__ __forceinline__ void stf(void* p, size_t i, float v, bool bf){
  if (bf) ((unsigned short*)p)[i] = f2bf(v);
  else    ((float*)p)[i] = v;
}
__device__ __forceinline__ float bflo(unsigned int q){
  union { unsigned int i; float f; } v; v.i = q << 16; return v.f;
}
__device__ __forceinline__ float bfhi(unsigned int q){
  union { unsigned int i; float f; } v; v.i = q & 0xffff0000u; return v.f;
}
// dot of a 200-long input row with f32 LDS x[200]
__device__ __forceinline__ float dotF(const void* wp, size_t off, const float* x, bool bf){
  float a0=0.f,a1=0.f,a2=0.f,a3=0.f;
  if (bf){
    const uint4* p = (const uint4*)((const unsigned short*)wp + off);
#pragma unroll
    for (int c = 0; c < FDIM/8; ++c){
      uint4 q = p[c];
      const float* xb = x + c*8;
      a0 += bflo(q.x)*xb[0]; a1 += bfhi(q.x)*xb[1];
      a2 += bflo(q.y)*xb[2]; a3 += bfhi(q.y)*xb[3];
      a0 += bflo(q.z)*xb[4]; a1 += bfhi(q.z)*xb[5];
      a2 += bflo(q.w)*xb[6]; a3 += bfhi(q.w)*xb[7];
    }
  } else {
    const float4* p = (const float4*)((const float*)wp + off);
#pragma unroll
    for (int c = 0; c < FDIM/4; ++c){
      float4 q = p[c];
      const float* xb = x + c*4;
      a0 += q.x*xb[0]; a1 += q.y*xb[1]; a2 += q.z*xb[2]; a3 += q.w*xb[3];
    }
  }
  return (a0+a1)+(a2+a3);
}
__device__ __forceinline__ float sigm(float x){ return 1.f/(1.f+__expf(-x)); }
__device__ __forceinline__ float tanh_(float x){
  float cx = fminf(fmaxf(x, -15.f), 15.f);
  float e = __expf(2.f*cx);
  return (e - 1.f)/(e + 1.f);
}
__device__ __forceinline__ float elu_(float x){ return x > 0.f ? x : __expf(x) - 1.f; }

// ---------- dtype probe: atom_mask is all 1.0 ----------
__global__ void k_probe(const unsigned int* __restrict__ amask, int* __restrict__ mode){
  if (blockIdx.x == 0 && threadIdx.x == 0)
    *mode = (amask[0] == 0x3F803F80u) ? 1 : 0;
}

// ---------- weight repack: all GEMM weights -> bf16 [row,200] k-contiguous in ws ----------
// layout (rows): 0 mwhh(600) | 600 maw_ctx(200) | 800 mwih(600) |
//   1400+1800d: alw_self(200)|alw_nbr(200)|atw(200)|gwhh(600) , +1200: gwih(600)  (d=0,1)
//   5000: afw(39)|zero(1)|bfw_self(10)|bfw_nbr(10)|zero(4)
__global__ __launch_bounds__(256) void k_repack(unsigned short* __restrict__ wrep,
    const void* mwhh, const void* maw, const void* mwih,
    const void* alw, const void* atw, const void* gwhh, const void* gwih,
    const void* afw, const void* bfw, const int* __restrict__ mode){
  const bool bf = (*mode != 0);
  int r = blockIdx.x, t = threadIdx.x;
  if (t >= FDIM) return;
  const void* S = nullptr; size_t src = 0;
  if (r < 600)      { S = mwhh; src = (size_t)r*200 + t; }
  else if (r < 800) { S = maw;  src = (size_t)(r-600)*400 + 200 + t; }
  else if (r < 1400){ S = mwih; src = (size_t)(r-800)*200 + t; }
  else if (r < 5000){
    int rr = r - 1400, d = rr / 1800, q = rr - d*1800;
    if (q < 200)      { S = alw;  src = (size_t)d*80000 + (size_t)q*400 + t; }
    else if (q < 400) { S = alw;  src = (size_t)d*80000 + (size_t)(q-200)*400 + 200 + t; }
    else if (q < 600) { S = atw;  src = (size_t)d*40000 + (size_t)(q-400)*200 + t; }
    else if (q < 1200){ S = gwhh; src = (size_t)d*120000 + (size_t)(q-600)*200 + t; }
    else              { S = gwih; src = (size_t)d*120000 + (size_t)(q-1200)*200 + t; }
  } else {
    int q = r - 5000;
    if (q < 39)       { S = afw; src = (size_t)q*200 + t; }
    else if (q >= 40 && q < 50) { S = bfw; src = (size_t)(q-40)*400 + t; }
    else if (q >= 50 && q < 60) { S = bfw; src = (size_t)(q-50)*400 + 200 + t; }
  }
  wrep[(size_t)r*FDIM + t] = S ? f2bf(ldf(S, src, bf)) : (unsigned short)0;
}

// ---------- GEMM: C[m,n] = sum_k A[m,k]*W[n,k]; A bf16 [rows,200], W bf16 repacked ----------
// block 256 thr (4 waves), tile 64x64; wave w: rows w*16..+16, 4 n-subtiles
__global__ __launch_bounds__(256) void k_gemm(
    const unsigned short* __restrict__ A,
    const unsigned short* __restrict__ W,
    unsigned short* __restrict__ C, int ldc, int Nout)
{
  __shared__ unsigned short As[64*LDA];
  __shared__ unsigned short Ws[64*LDA];
  int t = threadIdx.x;
  int mbase = blockIdx.y * 64;
  int nbase = blockIdx.x * 64;
  const uint4* Ag = (const uint4*)(A + (size_t)mbase*FDIM);
  for (int i = t; i < 64*25; i += 256){
    int r = i/25, c = i - r*25;
    *(uint4*)(As + r*LDA + c*8) = Ag[(size_t)r*25 + c];
  }
  for (int i = t; i < 64*25; i += 256){
    int r = i/25, c = i - r*25;
    int n = nbase + r;
    uint4 q = {0,0,0,0};
    if (n < Nout) q = *(const uint4*)(W + (size_t)n*FDIM + c*8);
    *(uint4*)(Ws + r*LDA + c*8) = q;
  }
  for (int i = t; i < 64*4; i += 256){     // zero-pad k = 200..232
    int r = i/4, c = i - r*4;
    uint4 z = {0,0,0,0};
    *(uint4*)(As + r*LDA + FDIM + c*8) = z;
    *(uint4*)(Ws + r*LDA + FDIM + c*8) = z;
  }
  __syncthreads();
  int wave = t >> 6, lane = t & 63;
  const unsigned short* Ap = As + (wave*16 + (lane & 15))*LDA + (lane >> 4)*8;
  const unsigned short* Wp = Ws + (lane & 15)*LDA + (lane >> 4)*8;
  v4f a0 = {0.f,0.f,0.f,0.f}, a1 = a0, a2 = a0, a3 = a0;
#pragma unroll
  for (int ks = 0; ks < 7; ks++){
    v8s a  = *(const v8s*)(Ap + ks*32);
    v8s b0 = *(const v8s*)(Wp + ks*32);
    v8s b1 = *(const v8s*)(Wp + 16*LDA + ks*32);
    v8s b2 = *(const v8s*)(Wp + 32*LDA + ks*32);
    v8s b3 = *(const v8s*)(Wp + 48*LDA + ks*32);
    a0 = __builtin_amdgcn_mfma_f32_16x16x32_bf16(a, b0, a0, 0, 0, 0);
    a1 = __builtin_amdgcn_mfma_f32_16x16x32_bf16(a, b1, a1, 0, 0, 0);
    a2 = __builtin_amdgcn_mfma_f32_16x16x32_bf16(a, b2, a2, 0, 0, 0);
    a3 = __builtin_amdgcn_mfma_f32_16x16x32_bf16(a, b3, a3, 0, 0, 0);
  }
  int col0 = nbase + (lane & 15);
  int r0 = mbase + wave*16 + (lane >> 4)*4;
  v4f accs[4] = {a0, a1, a2, a3};
#pragma unroll
  for (int j = 0; j < 4; j++){
    int col = col0 + j*16;
    if (col < Nout){
#pragma unroll
      for (int reg = 0; reg < 4; reg++)
        C[(size_t)(r0+reg)*ldc + col] = f2bf(accs[j][reg]);
    }
  }
}

// ---------- pre_mol[b,f] = mab[f] + dot(mol[b], maw[f, :F]) ----------
__global__ __launch_bounds__(256) void k_premol(float* __restrict__ pre,
    const void* __restrict__ molf, const void* __restrict__ maw,
    const void* __restrict__ mab, const int* __restrict__ mode){
  const bool bf = (*mode != 0);
  int b = blockIdx.x, t = threadIdx.x;
  __shared__ float mf[FDIM];
  for (int f = t; f < FDIM; f += 256) mf[f] = ldf(molf, (size_t)b*FDIM+f, bf);
  __syncthreads();
  for (int f = t; f < FDIM; f += 256)
    pre[b*FDIM+f] = ldf(mab, f, bf) + dotF(maw, (size_t)f*2*FDIM, mf, bf);
}

// ---------- mw[b,l] = softmax_l(dot(act[b,l], mol[b])) ----------
__global__ __launch_bounds__(LL) void k_gitdot(float* __restrict__ mw_out,
    const void* __restrict__ molf, const void* __restrict__ actf,
    const int* __restrict__ mode){
  const bool bf = (*mode != 0);
  int b = blockIdx.x, l = threadIdx.x;
  __shared__ float mf[FDIM];
  __shared__ float red[LL];
  for (int f = l; f < FDIM; f += LL) mf[f] = ldf(molf, (size_t)b*FDIM+f, bf);
  __syncthreads();
  float d = dotF(actf, ((size_t)b*LL + l)*FDIM, mf, bf);
  red[l] = d; __syncthreads();
  for (int s = 128; s > 0; s >>= 1){ if (l < s) red[l] = fmaxf(red[l], red[l+s]); __syncthreads(); }
  float m = red[0]; __syncthreads();
  float e = __expf(d - m);
  red[l] = e; __syncthreads();
  for (int s = 128; s > 0; s >>= 1){ if (l < s) red[l] += red[l+s]; __syncthreads(); }
  mw_out[(size_t)b*LL + l] = e / red[0];
}

// ---------- act[row,f] = mw[row]*mol[b,f] + actf[row,f]  (8-wide vectorized) ----------
__global__ __launch_bounds__(256) void k_gitwrite(unsigned short* __restrict__ act,
    const void* __restrict__ molf, const void* __restrict__ actf,
    const float* __restrict__ mw, const int* __restrict__ mode){
  const bool bf = (*mode != 0);
  int idx = blockIdx.x*256 + threadIdx.x;
  if (idx >= BL*25) return;
  int row = idx/25, f0 = (idx - row*25)*8;
  int b = row >> 8;
  float m = mw[row];
  size_t ab = (size_t)row*FDIM + f0, mb = (size_t)b*FDIM + f0;
  float v[8];
#pragma unroll
  for (int j = 0; j < 8; j++) v[j] = m*ldf(molf, mb+j, bf) + ldf(actf, ab+j, bf);
  uint4 q;
  q.x = (unsigned int)f2bf(v[0]) | ((unsigned int)f2bf(v[1]) << 16);
  q.y = (unsigned int)f2bf(v[2]) | ((unsigned int)f2bf(v[3]) << 16);
  q.z = (unsigned int)f2bf(v[4]) | ((unsigned int)f2bf(v[5]) << 16);
  q.w = (unsigned int)f2bf(v[6]) | ((unsigned int)f2bf(v[7]) << 16);
  *(uint4*)(act + ab) = q;
}

// ---------- ctx <- elu(pre[b] + ctx) in place ----------
__global__ __launch_bounds__(256) void k_ctx_ew(unsigned short* __restrict__ ctx,
    const float* __restrict__ pre, int base){
  int a = blockIdx.x, t = threadIdx.x;
  if (t < FDIM){
    int b = (base + a) >> 8;
    float v = pre[b*FDIM + t] + bf2f(ctx[(size_t)a*FDIM + t]);
    ctx[(size_t)a*FDIM + t] = f2bf(elu_(v));
  }
}

// ---------- GRU elementwise from big[a*1200 + off] ----------
__global__ __launch_bounds__(256) void k_gru_ew(unsigned short* __restrict__ act,
    const unsigned short* __restrict__ big, int gio, int gho,
    const void* __restrict__ bih, const void* __restrict__ bhh,
    unsigned long long ob, int dorelu, const int* __restrict__ mode){
  const bool bf = (*mode != 0);
  int a = blockIdx.x, t = threadIdx.x;
  if (t < FDIM){
    size_t g = (size_t)a*1200;
    float gir = bf2f(big[g + gio + t])          + ldf(bih, ob + t, bf);
    float giz = bf2f(big[g + gio + FDIM + t])   + ldf(bih, ob + FDIM + t, bf);
    float gin = bf2f(big[g + gio + 2*FDIM + t]) + ldf(bih, ob + 2*FDIM + t, bf);
    float ghr = bf2f(big[g + gho + t])          + ldf(bhh, ob + t, bf);
    float ghz = bf2f(big[g + gho + FDIM + t])   + ldf(bhh, ob + FDIM + t, bf);
    float ghn = bf2f(big[g + gho + 2*FDIM + t]) + ldf(bhh, ob + 2*FDIM + t, bf);
    float r = sigm(gir + ghr);
    float z = sigm(giz + ghz);
    float n = tanh_(gin + r*ghn);
    float h = bf2f(act[(size_t)a*FDIM + t]);
    float hn = (1.f - z)*n + z*h;
    if (dorelu) hn = fmaxf(hn, 0.f);
    act[(size_t)a*FDIM + t] = f2bf(hn);
  }
}

// ---------- attention ew: big cols [S|P|Q] -> ctx ----------
__global__ __launch_bounds__(256) void k_attn_ew(const unsigned short* __restrict__ big,
    unsigned short* __restrict__ ctx, const int* __restrict__ adeg,
    const void* __restrict__ alb, const void* __restrict__ atb,
    unsigned long long boff, int base, const int* __restrict__ mode){
  const bool bf = (*mode != 0);
  int a = blockIdx.x, t = threadIdx.x;
  __shared__ int   nidx[NN];
  __shared__ float nmadd[NN], nmmul[NN];
  if (t < NN){
    int idx = adeg[((size_t)(base + a))*NN + t];
    nidx[t] = ((a >> 8) << 8) + idx;       // chunk-local neighbor row
    bool pad = (idx == LL-1);
    nmadd[t] = pad ? -9e8f : 0.f;
    nmmul[t] = pad ? 0.f : 1.f;
  }
  __syncthreads();
  if (t < FDIM){
    float s0 = bf2f(big[(size_t)a*1200 + t]) + ldf(alb, boff + t, bf);
    float atbv = ldf(atb, boff + t, bf);
    float sc[NN];
#pragma unroll
    for (int n = 0; n < NN; n++){
      float s = s0 + bf2f(big[(size_t)nidx[n]*1200 + 200 + t]);
      s = s > 0.f ? s : 0.01f*s;
      sc[n] = s + nmadd[n];
    }
    float m = -1e30f;
#pragma unroll
    for (int n = 0; n < NN; n++) m = fmaxf(m, sc[n]);
    float e[NN]; float sum = 0.f;
#pragma unroll
    for (int n = 0; n < NN; n++){ e[n] = __expf(sc[n] - m); sum += e[n]; }
    float inv = 1.f/sum, acc = 0.f;
#pragma unroll
    for (int n = 0; n < NN; n++){
      float nt = bf2f(big[(size_t)nidx[n]*1200 + 400 + t]) + atbv;
      acc += e[n]*inv*nmmul[n]*nt;
    }
    ctx[(size_t)a*FDIM + t] = f2bf(elu_(acc));
  }
}

// ---------- atom decode ew: AL = big[a*64 + 0..39] ----------
__global__ __launch_bounds__(64) void k_atom_ew(const unsigned short* __restrict__ big,
    const void* __restrict__ afb, void* __restrict__ out, int base,
    const int* __restrict__ mode){
  const bool bf = (*mode != 0);
  int a = blockIdx.x, t = threadIdx.x;
  __shared__ float al[AOUTD];
  __shared__ float segm[4], segs[4];
  const int lo[4] = {0,16,24,31}, hi[4] = {16,22,30,36};
  if (t < AOUTD) al[t] = bf2f(big[(size_t)a*64 + t]) + ldf(afb, t, bf);
  __syncthreads();
  if (t < 4){
    float m = -1e30f;
    for (int k = lo[t]; k < hi[t]; k++) m = fmaxf(m, al[k]);
    float s = 0.f;
    for (int k = lo[t]; k < hi[t]; k++) s += __expf(al[k]-m);
    segm[t] = m; segs[t] = s;
  }
  __syncthreads();
  if (t < AOUTD){
    float v = 0.f;
#pragma unroll
    for (int g = 0; g < 4; g++)
      if (t >= lo[g] && t < hi[g]) v += __expf(al[t]-segm[g])/segs[g];
    if (t == 24) v += fmaxf(al[24], 0.f);
    if (t == 30 || t == 36 || t == 37 || t == 38) v += sigm(al[t]);
    stf(out, (size_t)(base + a)*AOUTD + t, v, bf);
  }
}

// ---------- bond decode ew: U = big[.,40..50], V = big[nbr,50..60] ----------
__global__ __launch_bounds__(64) void k_bond_ew(const unsigned short* __restrict__ big,
    const int* __restrict__ adeg, const void* __restrict__ bfb,
    void* __restrict__ out, int base, const int* __restrict__ mode){
  const bool bf = (*mode != 0);
  const size_t obase = (size_t)BL*AOUTD;
  int a = blockIdx.x, t = threadIdx.x;
  if (t < NN){
    int idx = adeg[((size_t)(base + a))*NN + t];
    int vr = ((a >> 8) << 8) + idx;
    float bl[BOUTD];
#pragma unroll
    for (int o = 0; o < BOUTD; o++)
      bl[o] = bf2f(big[(size_t)a*64 + 40 + o]) + bf2f(big[(size_t)vr*64 + 50 + o])
            + ldf(bfb, o, bf);
    float v[BOUTD];
    float m0 = fmaxf(fmaxf(bl[0],bl[1]), fmaxf(bl[2],bl[3]));
    float e0[4], s0 = 0.f;
#pragma unroll
    for (int j = 0; j < 4; j++){ e0[j] = __expf(bl[j]-m0); s0 += e0[j]; }
    float m1 = fmaxf(fmaxf(bl[6],bl[7]), fmaxf(bl[8],bl[9]));
    float e1[4], s1 = 0.f;
#pragma unroll
    for (int j = 0; j < 4; j++){ e1[j] = __expf(bl[6+j]-m1); s1 += e1[j]; }
#pragma unroll
    for (int j = 0; j < 4; j++) v[j] = e0[j]/s0;
    v[4] = sigm(bl[4]); v[5] = sigm(bl[5]);
#pragma unroll
    for (int j = 0; j < 4; j++) v[6+j] = e1[j]/s1;
    size_t op = obase + ((size_t)(base + a)*NN + t)*BOUTD;
#pragma unroll
    for (int j = 0; j < BOUTD; j++) stf(out, op + j, v[j], bf);
  }
}

extern "C" void kernel_launch(void* const* d_in, const int* in_sizes, int n_in,
                              void* d_out, int out_size, void* d_ws, size_t ws_size,
                              hipStream_t stream) {
  const int* adeg = (const int*)d_in[2];
  const void* amask = d_in[4];
  const void* molf = d_in[5];
  const void* actf = d_in[6];
  const void* afw = d_in[7];  const void* afb = d_in[8];
  const void* bfw = d_in[9];  const void* bfb = d_in[10];
  const void* alw = d_in[11]; const void* alb = d_in[12];
  const void* atw = d_in[13]; const void* atb = d_in[14];
  const void* gwih = d_in[15]; const void* gwhh = d_in[16];
  const void* gbih = d_in[17]; const void* gbhh = d_in[18];
  const void* maw = d_in[19]; const void* mab = d_in[20];
  const void* mwih = d_in[21]; const void* mwhh = d_in[22];
  const void* mbih = d_in[23]; const void* mbhh = d_in[24];

  // ---- ws layout: fixed part, then CH-dependent ctx/big ----
  char* w = (char*)d_ws;
  unsigned short* act  = (unsigned short*)w;  w += (size_t)BL*FDIM*2;           // 13.11 MB
  float*          mw   = (float*)w;           w += (size_t)BL*4;                // 131 KB
  float*          pre  = (float*)w;           w += (size_t)BB*FDIM*4;           // 102 KB
  unsigned short* wrep = (unsigned short*)w;  w += (size_t)WREP_ROWS*FDIM*2;    // 2.03 MB
  int*            mode = (int*)w;             w += 16;
  size_t fixed = (size_t)(w - (char*)d_ws);
  // runtime chunk size: per-chunk bytes = CH*(200+1200)*2 = CH*2800
  int CH = 8192;
  if (ws_size >= fixed + (size_t)32768*2800) CH = 32768;
  else if (ws_size >= fixed + (size_t)16384*2800) CH = 16384;
  unsigned short* ctx = (unsigned short*)w;   w += (size_t)CH*FDIM*2;
  unsigned short* big = (unsigned short*)w;
  const int NCH = BL / CH;

  // repacked weight row offsets
  unsigned short* WmolGH  = wrep;                      // mwhh   [600]
  unsigned short* WmolCTX = wrep + (size_t)600*FDIM;   // maw_n  [200]
  unsigned short* WmolGI  = wrep + (size_t)800*FDIM;   // mwih   [600]
  unsigned short* Wdec    = wrep + (size_t)5000*FDIM;  // afw|bfwU|bfwV [64]

  const dim3 gB(256);
  k_probe<<<1, 64, 0, stream>>>((const unsigned int*)amask, mode);
  k_repack<<<WREP_ROWS, 256, 0, stream>>>(wrep, mwhh, maw, mwih, alw, atw, gwhh, gwih,
                                          afw, bfw, mode);
  k_premol<<<BB, 256, 0, stream>>>(pre, molf, maw, mab, mode);
  k_gitdot<<<BB, LL, 0, stream>>>(mw, molf, actf, mode);
  k_gitwrite<<<(BL*25 + 255)/256, 256, 0, stream>>>(act, molf, actf, mw, mode);

  const int GY = CH/64;
  // ---- mol GRU x2 ----
  for (int ts = 0; ts < 2; ts++){
    for (int c = 0; c < NCH; c++){
      int base = c*CH;
      unsigned short* Ac = act + (size_t)base*FDIM;
      k_gemm<<<dim3(10, GY), gB, 0, stream>>>(Ac, WmolGH, big, 1200, 600);       // gh -> cols 0..600
      k_gemm<<<dim3(4,  GY), gB, 0, stream>>>(Ac, WmolCTX, ctx, FDIM, FDIM);     // ctx_raw
      k_ctx_ew<<<CH, 256, 0, stream>>>(ctx, pre, base);
      k_gemm<<<dim3(10, GY), gB, 0, stream>>>(ctx, WmolGI, big + 600, 1200, 600);// gi -> cols 600..1200
      k_gru_ew<<<CH, 256, 0, stream>>>(Ac, big, 600, 0, mbih, mbhh, 0ull, (ts==1), mode);
    }
  }
  // ---- 2 attention+GRU rounds ----
  for (int d = 0; d < 2; d++){
    unsigned short* WrdA = wrep + (size_t)(1400 + 1800*d)*FDIM;  // S|P|Q|gh [1200]
    unsigned short* WrdB = wrep + (size_t)(2600 + 1800*d)*FDIM;  // gwih [600]
    unsigned long long ob = (unsigned long long)d*FDIM;
    unsigned long long ogb = (unsigned long long)d*3*FDIM;
    for (int c = 0; c < NCH; c++){
      int base = c*CH;
      unsigned short* Ac = act + (size_t)base*FDIM;
      k_gemm<<<dim3(19, GY), gB, 0, stream>>>(Ac, WrdA, big, 1200, 1200);        // S|P|Q|gh
      k_attn_ew<<<CH, 256, 0, stream>>>(big, ctx, adeg, alb, atb, ob, base, mode);
      k_gemm<<<dim3(10, GY), gB, 0, stream>>>(ctx, WrdB, big, 1200, 600);        // gi -> cols 0..600
      k_gru_ew<<<CH, 256, 0, stream>>>(Ac, big, 0, 600, gbih, gbhh, ogb, 1, mode);
    }
  }
  // ---- decode ----
  for (int c = 0; c < NCH; c++){
    int base = c*CH;
    unsigned short* Ac = act + (size_t)base*FDIM;
    k_gemm<<<dim3(1, GY), gB, 0, stream>>>(Ac, Wdec, big, 64, 60);               // AL|U|V
    k_atom_ew<<<CH, 64, 0, stream>>>(big, afb, d_out, base, mode);
    k_bond_ew<<<CH, 64, 0, stream>>>(big, adeg, bfb, d_out, base, mode);
  }
}

// Round 6
// 932.868 us; speedup vs baseline: 27.6899x; 1.0768x over previous
//
#include <hip/hip_runtime.h>
#include <hip/hip_bf16.h>

#define FDIM 200
#define BB   128
#define LL   256
#define NN   8
#define BL   (BB*LL)
#define AOUTD 39
#define BOUTD 10
#define KCH  28            // K chunks of 8 elems (224 = 7 MFMA steps x 32)

// chunk-major weight panels (16B chunk index bases)
#define P0 0               // mol gh  (mwhh)   Ng=640  N=600
#define P1 17920           // mol ctx (maw_n)  Ng=256  N=200
#define P2 25088           // mol gi  (mwih)   Ng=640  N=600
#define P3 43008           // rd0 S|P|Q|gh     Ng=1280 N=1200
#define P4 78848           // rd0 gi  (gwih)   Ng=640  N=600
#define P5 96768           // rd1 S|P|Q|gh     Ng=1280 N=1200
#define P6 132608          // rd1 gi           Ng=640  N=600
#define P7 150528          // dec AL|U|V       Ng=128  N=64
#define WCHUNKS 154112

typedef short v8s __attribute__((ext_vector_type(8)));
typedef float v4f __attribute__((ext_vector_type(4)));

// ---------- dtype helpers (runtime bf16-vs-f32 mode for INPUT tensors) ----------
__device__ __forceinline__ float bf2f(unsigned short u){
  union { unsigned int i; float f; } v; v.i = ((unsigned int)u) << 16; return v.f;
}
__device__ __forceinline__ unsigned short f2bf(float f){
  unsigned int x = __float_as_uint(f);
  x += 0x7fffu + ((x >> 16) & 1u);   // RNE
  return (unsigned short)(x >> 16);
}
__device__ __forceinline__ float ldf(const void* p, long long i, bool bf){
  return bf ? bf2f(((const unsigned short*)p)[i]) : ((const float*)p)[i];
}
__device__ __forceinline__ void stf(void* p, size_t i, float v, bool bf){
  if (bf) ((unsigned short*)p)[i] = f2bf(v);
  else    ((float*)p)[i] = v;
}
__device__ __forceinline__ float bflo(unsigned int q){
  union { unsigned int i; float f; } v; v.i = q << 16; return v.f;
}
__device__ __forceinline__ float bfhi(unsigned int q){
  union { unsigned int i; float f; } v; v.i = q & 0xffff0000u; return v.f;
}
__device__ __forceinline__ void ld8(const unsigned short* p, float* o){
  uint4 q = *(const uint4*)p;
  o[0]=bflo(q.x); o[1]=bfhi(q.x); o[2]=bflo(q.y); o[3]=bfhi(q.y);
  o[4]=bflo(q.z); o[5]=bfhi(q.z); o[6]=bflo(q.w); o[7]=bfhi(q.w);
}
__device__ __forceinline__ void st8(unsigned short* p, const float* v){
  uint4 q;
  q.x = (unsigned int)f2bf(v[0]) | ((unsigned int)f2bf(v[1]) << 16);
  q.y = (unsigned int)f2bf(v[2]) | ((unsigned int)f2bf(v[3]) << 16);
  q.z = (unsigned int)f2bf(v[4]) | ((unsigned int)f2bf(v[5]) << 16);
  q.w = (unsigned int)f2bf(v[6]) | ((unsigned int)f2bf(v[7]) << 16);
  *(uint4*)p = q;
}
// dot of a 200-long input row with f32 LDS x[200]
__device__ __forceinline__ float dotF(const void* wp, size_t off, const float* x, bool bf){
  float a0=0.f,a1=0.f,a2=0.f,a3=0.f;
  if (bf){
    const uint4* p = (const uint4*)((const unsigned short*)wp + off);
#pragma unroll
    for (int c = 0; c < FDIM/8; ++c){
      uint4 q = p[c];
      const float* xb = x + c*8;
      a0 += bflo(q.x)*xb[0]; a1 += bfhi(q.x)*xb[1];
      a2 += bflo(q.y)*xb[2]; a3 += bfhi(q.y)*xb[3];
      a0 += bflo(q.z)*xb[4]; a1 += bfhi(q.z)*xb[5];
      a2 += bflo(q.w)*xb[6]; a3 += bfhi(q.w)*xb[7];
    }
  } else {
    const float4* p = (const float4*)((const float*)wp + off);
#pragma unroll
    for (int c = 0; c < FDIM/4; ++c){
      float4 q = p[c];
      const float* xb = x + c*4;
      a0 += q.x*xb[0]; a1 += q.y*xb[1]; a2 += q.z*xb[2]; a3 += q.w*xb[3];
    }
  }
  return (a0+a1)+(a2+a3);
}
__device__ __forceinline__ float sigm(float x){ return 1.f/(1.f+__expf(-x)); }
__device__ __forceinline__ float tanh_(float x){
  float cx = fminf(fmaxf(x, -15.f), 15.f);
  float e = __expf(2.f*cx);
  return (e - 1.f)/(e + 1.f);
}
__device__ __forceinline__ float elu_(float x){ return x > 0.f ? x : __expf(x) - 1.f; }

// ---------- dtype probe: atom_mask is all 1.0 ----------
__global__ void k_probe(const unsigned int* __restrict__ amask, int* __restrict__ mode){
  if (blockIdx.x == 0 && threadIdx.x == 0)
    *mode = (amask[0] == 0x3F803F80u) ? 1 : 0;
}

// ---------- weight repack -> chunk-major bf16 panels: chunk idx = base + c*Ng + n ----------
__global__ __launch_bounds__(256) void k_repack(unsigned short* __restrict__ wrep,
    const void* mwhh, const void* maw, const void* mwih,
    const void* alw, const void* atw, const void* gwhh, const void* gwih,
    const void* afw, const void* bfw, const int* __restrict__ mode){
  const bool bf = (*mode != 0);
  int idx = blockIdx.x*256 + threadIdx.x;
  if (idx >= WCHUNKS) return;
  int pb, Ng;
  if (idx < P1)      { pb = P0; Ng = 640;  }
  else if (idx < P2) { pb = P1; Ng = 256;  }
  else if (idx < P3) { pb = P2; Ng = 640;  }
  else if (idx < P4) { pb = P3; Ng = 1280; }
  else if (idx < P5) { pb = P4; Ng = 640;  }
  else if (idx < P6) { pb = P5; Ng = 1280; }
  else if (idx < P7) { pb = P6; Ng = 640;  }
  else               { pb = P7; Ng = 128;  }
  int li = idx - pb;
  int c = li / Ng, n = li - c*Ng;
  const void* S = nullptr; long long sb = 0; int rl = 0, off = 0, row = 0, N = 0;
  if (pb == P0)      { S = mwhh; rl = 200; row = n; N = 600; }
  else if (pb == P1) { S = maw;  rl = 400; off = 200; row = n; N = 200; }
  else if (pb == P2) { S = mwih; rl = 200; row = n; N = 600; }
  else if (pb == P3 || pb == P5){
    long long d = (pb == P5) ? 1 : 0; N = 1200;
    if (n < 200)      { S = alw;  sb = d*80000;  rl = 400; off = 0;   row = n; }
    else if (n < 400) { S = alw;  sb = d*80000;  rl = 400; off = 200; row = n-200; }
    else if (n < 600) { S = atw;  sb = d*40000;  rl = 200; off = 0;   row = n-400; }
    else              { S = gwhh; sb = d*120000; rl = 200; off = 0;   row = n-600; }
  }
  else if (pb == P4 || pb == P6){
    long long d = (pb == P6) ? 1 : 0;
    S = gwih; sb = d*120000; rl = 200; row = n; N = 600;
  } else {
    N = 64;
    if (n < 39)                { S = afw; rl = 200; row = n; }
    else if (n >= 40 && n < 50){ S = bfw; rl = 400; off = 0;   row = n-40; }
    else if (n >= 50 && n < 60){ S = bfw; rl = 400; off = 200; row = n-50; }
  }
  float v[8];
#pragma unroll
  for (int j = 0; j < 8; j++){
    int k = c*8 + j;
    v[j] = (S && n < N && k < 200) ? ldf(S, sb + (long long)row*rl + off + k, bf) : 0.f;
  }
  st8(wrep + (size_t)idx*8, v);
}

// ---------- GEMM: C[m,n] = sum_k A[m,k]*W[n,k], K=200 (padded 224) ----------
// Wc chunk-major [KCH][wNg]; block 256 thr = 4 waves; tile 128x128; wave: 32 rows x 128 cols
__global__ __launch_bounds__(256, 2) void k_gemm(
    const unsigned short* __restrict__ A,
    const unsigned short* __restrict__ Wc, int wNg,
    unsigned short* __restrict__ C, int ldc, int Nout)
{
  __shared__ unsigned short Ws[KCH*128*8];    // 57,344 B
  int t = threadIdx.x;
  int nbase = blockIdx.x * 128;
  int mbase = blockIdx.y * 128;
  const uint4* Wg = (const uint4*)Wc;
  uint4* Wl = (uint4*)Ws;
  for (int i = t; i < KCH*128; i += 256){     // linear LDS write: conflict-free
    int c = i >> 7, n = i & 127;
    Wl[i] = Wg[(size_t)c*wNg + nbase + n];
  }
  __syncthreads();
  int wave = t >> 6, lane = t & 63;
  int quad = lane >> 4, l16 = lane & 15;
  const unsigned short* A0 = A + (size_t)(mbase + wave*32 + l16)*FDIM + quad*8;
  v4f acc[2][8];
#pragma unroll
  for (int ms = 0; ms < 2; ms++)
#pragma unroll
    for (int ns = 0; ns < 8; ns++) acc[ms][ns] = (v4f){0.f,0.f,0.f,0.f};
#pragma unroll
  for (int ks = 0; ks < 7; ks++){
    v8s a0 = *(const v8s*)(A0 + ks*32);              // k>=200 garbage x zero-W = 0
    v8s a1 = *(const v8s*)(A0 + 16*FDIM + ks*32);
    const unsigned short* Bp = Ws + ((ks*4 + quad)*128 + l16)*8;
#pragma unroll
    for (int ns = 0; ns < 8; ns++){
      v8s b = *(const v8s*)(Bp + ns*128);            // 16 lanes consecutive 16B: conflict-free
      acc[0][ns] = __builtin_amdgcn_mfma_f32_16x16x32_bf16(a0, b, acc[0][ns], 0, 0, 0);
      acc[1][ns] = __builtin_amdgcn_mfma_f32_16x16x32_bf16(a1, b, acc[1][ns], 0, 0, 0);
    }
  }
  int colb = nbase + l16;
  int rowb = mbase + wave*32 + quad*4;
#pragma unroll
  for (int ms = 0; ms < 2; ms++){
#pragma unroll
    for (int ns = 0; ns < 8; ns++){
      int col = colb + ns*16;
      if (col < Nout){
        unsigned short* Cp = C + (size_t)(rowb + ms*16)*ldc + col;
#pragma unroll
        for (int reg = 0; reg < 4; reg++)
          Cp[(size_t)reg*ldc] = f2bf(acc[ms][ns][reg]);
      }
    }
  }
}

// ---------- pre_mol[b,f] = mab[f] + dot(mol[b], maw[f, :F]) ----------
__global__ __launch_bounds__(256) void k_premol(float* __restrict__ pre,
    const void* __restrict__ molf, const void* __restrict__ maw,
    const void* __restrict__ mab, const int* __restrict__ mode){
  const bool bf = (*mode != 0);
  int b = blockIdx.x, t = threadIdx.x;
  __shared__ float mf[FDIM];
  for (int f = t; f < FDIM; f += 256) mf[f] = ldf(molf, (size_t)b*FDIM+f, bf);
  __syncthreads();
  for (int f = t; f < FDIM; f += 256)
    pre[b*FDIM+f] = ldf(mab, f, bf) + dotF(maw, (size_t)f*2*FDIM, mf, bf);
}

// ---------- mw[b,l] = softmax_l(dot(act[b,l], mol[b])) ----------
__global__ __launch_bounds__(LL) void k_gitdot(float* __restrict__ mw_out,
    const void* __restrict__ molf, const void* __restrict__ actf,
    const int* __restrict__ mode){
  const bool bf = (*mode != 0);
  int b = blockIdx.x, l = threadIdx.x;
  __shared__ float mf[FDIM];
  __shared__ float red[LL];
  for (int f = l; f < FDIM; f += LL) mf[f] = ldf(molf, (size_t)b*FDIM+f, bf);
  __syncthreads();
  float d = dotF(actf, ((size_t)b*LL + l)*FDIM, mf, bf);
  red[l] = d; __syncthreads();
  for (int s = 128; s > 0; s >>= 1){ if (l < s) red[l] = fmaxf(red[l], red[l+s]); __syncthreads(); }
  float m = red[0]; __syncthreads();
  float e = __expf(d - m);
  red[l] = e; __syncthreads();
  for (int s = 128; s > 0; s >>= 1){ if (l < s) red[l] += red[l+s]; __syncthreads(); }
  mw_out[(size_t)b*LL + l] = e / red[0];
}

// ---------- act[row,f] = mw[row]*mol[b,f] + actf[row,f] ----------
__global__ __launch_bounds__(256) void k_gitwrite(unsigned short* __restrict__ act,
    const void* __restrict__ molf, const void* __restrict__ actf,
    const float* __restrict__ mw, const int* __restrict__ mode){
  const bool bf = (*mode != 0);
  int idx = blockIdx.x*256 + threadIdx.x;
  if (idx >= BL*25) return;
  int row = idx/25, f0 = (idx - row*25)*8;
  int b = row >> 8;
  float m = mw[row];
  size_t ab = (size_t)row*FDIM + f0, mb = (size_t)b*FDIM + f0;
  float v[8];
#pragma unroll
  for (int j = 0; j < 8; j++) v[j] = m*ldf(molf, mb+j, bf) + ldf(actf, ab+j, bf);
  st8(act + ab, v);
}

// ---------- ctx <- elu(pre[b] + ctx), 8-wide ----------
__global__ __launch_bounds__(256) void k_ctx_ew(unsigned short* __restrict__ ctx,
    const float* __restrict__ pre, int base, int total){
  int idx = blockIdx.x*256 + threadIdx.x;
  if (idx >= total) return;
  int row = idx/25, f0 = (idx - row*25)*8;
  int b = (base + row) >> 8;
  float x[8];
  ld8(ctx + (size_t)row*FDIM + f0, x);
#pragma unroll
  for (int j = 0; j < 8; j++) x[j] = elu_(pre[b*FDIM + f0 + j] + x[j]);
  st8(ctx + (size_t)row*FDIM + f0, x);
}

// ---------- GRU elementwise, 8-wide: act <- gru(big[gio..], big[gho..], act) ----------
__global__ __launch_bounds__(256) void k_gru_ew(unsigned short* __restrict__ act,
    const unsigned short* __restrict__ big, int gio, int gho,
    const void* __restrict__ bih, const void* __restrict__ bhh,
    long long ob, int dorelu, int total, const int* __restrict__ mode){
  const bool bf = (*mode != 0);
  int idx = blockIdx.x*256 + threadIdx.x;
  if (idx >= total) return;
  int row = idx/25, f0 = (idx - row*25)*8;
  size_t g = (size_t)row*1200;
  float gir[8], giz[8], gin[8], ghr[8], ghz[8], ghn[8], h[8], o[8];
  ld8(big + g + gio + f0,       gir);
  ld8(big + g + gio + 200 + f0, giz);
  ld8(big + g + gio + 400 + f0, gin);
  ld8(big + g + gho + f0,       ghr);
  ld8(big + g + gho + 200 + f0, ghz);
  ld8(big + g + gho + 400 + f0, ghn);
  ld8(act + (size_t)row*FDIM + f0, h);
#pragma unroll
  for (int j = 0; j < 8; j++){
    float r = sigm(gir[j] + ldf(bih, ob + f0 + j, bf) + ghr[j] + ldf(bhh, ob + f0 + j, bf));
    float z = sigm(giz[j] + ldf(bih, ob + 200 + f0 + j, bf) + ghz[j] + ldf(bhh, ob + 200 + f0 + j, bf));
    float n = tanh_(gin[j] + ldf(bih, ob + 400 + f0 + j, bf)
                    + r*(ghn[j] + ldf(bhh, ob + 400 + f0 + j, bf)));
    float hn = (1.f - z)*n + z*h[j];
    o[j] = dorelu ? fmaxf(hn, 0.f) : hn;
  }
  st8(act + (size_t)row*FDIM + f0, o);
}

// ---------- attention elementwise, 8-wide: big[S|P|Q] -> ctx ----------
__global__ __launch_bounds__(256) void k_attn_ew(const unsigned short* __restrict__ big,
    unsigned short* __restrict__ ctx, const int* __restrict__ adeg,
    const void* __restrict__ alb, const void* __restrict__ atb,
    long long boff, int base, int total, const int* __restrict__ mode){
  const bool bf = (*mode != 0);
  int idx = blockIdx.x*256 + threadIdx.x;
  if (idx >= total) return;
  int a = idx/25, f0 = (idx - a*25)*8;
  int mb = (a >> 8) << 8;
  float s0[8], atbv[8];
  ld8(big + (size_t)a*1200 + f0, s0);
#pragma unroll
  for (int j = 0; j < 8; j++){
    s0[j] += ldf(alb, boff + f0 + j, bf);
    atbv[j] = ldf(atb, boff + f0 + j, bf);
  }
  int nid[NN]; float nmul[NN], nadd[NN];
#pragma unroll
  for (int n = 0; n < NN; n++){
    int iv = adeg[((size_t)(base + a))*NN + n];
    nid[n] = mb + iv;
    bool pad = (iv == LL-1);
    nmul[n] = pad ? 0.f : 1.f;
    nadd[n] = pad ? -9e8f : 0.f;
  }
  float e[NN][8], mx[8];
#pragma unroll
  for (int j = 0; j < 8; j++) mx[j] = -1e30f;
#pragma unroll
  for (int n = 0; n < NN; n++){
    float p[8];
    ld8(big + (size_t)nid[n]*1200 + 200 + f0, p);
#pragma unroll
    for (int j = 0; j < 8; j++){
      float s = s0[j] + p[j];
      s = s > 0.f ? s : 0.01f*s;
      s += nadd[n];
      e[n][j] = s;
      mx[j] = fmaxf(mx[j], s);
    }
  }
  float sum[8] = {0,0,0,0,0,0,0,0};
#pragma unroll
  for (int n = 0; n < NN; n++)
#pragma unroll
    for (int j = 0; j < 8; j++){ e[n][j] = __expf(e[n][j] - mx[j]); sum[j] += e[n][j]; }
  float acc[8] = {0,0,0,0,0,0,0,0};
#pragma unroll
  for (int n = 0; n < NN; n++){
    float q[8];
    ld8(big + (size_t)nid[n]*1200 + 400 + f0, q);
#pragma unroll
    for (int j = 0; j < 8; j++) acc[j] += e[n][j]*nmul[n]*(q[j] + atbv[j]);
  }
  float o[8];
#pragma unroll
  for (int j = 0; j < 8; j++) o[j] = elu_(acc[j]/sum[j]);
  st8(ctx + (size_t)a*FDIM + f0, o);
}

// ---------- merged decode: 4 atoms/block; atom (tl<39) + bond (tl in 40..47) ----------
__global__ __launch_bounds__(256) void k_dec(const unsigned short* __restrict__ big,
    const int* __restrict__ adeg, const void* __restrict__ afb,
    const void* __restrict__ bfb, void* __restrict__ out, int base,
    const int* __restrict__ mode){
  const bool bf = (*mode != 0);
  const size_t obase = (size_t)BL*AOUTD;
  int sub = threadIdx.x >> 6, tl = threadIdx.x & 63;
  int a = blockIdx.x*4 + sub;
  __shared__ float al[4][40];
  __shared__ float sm[4][4], ss[4][4];
  const int lo[4] = {0,16,24,31}, hi[4] = {16,22,30,36};
  if (tl < AOUTD) al[sub][tl] = bf2f(big[(size_t)a*64 + tl]) + ldf(afb, tl, bf);
  __syncthreads();
  if (tl < 4){
    float m = -1e30f;
    for (int k = lo[tl]; k < hi[tl]; k++) m = fmaxf(m, al[sub][k]);
    float s = 0.f;
    for (int k = lo[tl]; k < hi[tl]; k++) s += __expf(al[sub][k]-m);
    sm[sub][tl] = m; ss[sub][tl] = s;
  }
  __syncthreads();
  if (tl < AOUTD){
    float v = 0.f;
#pragma unroll
    for (int g = 0; g < 4; g++)
      if (tl >= lo[g] && tl < hi[g]) v += __expf(al[sub][tl]-sm[sub][g])/ss[sub][g];
    if (tl == 24) v += fmaxf(al[sub][24], 0.f);
    if (tl == 30 || tl == 36 || tl == 37 || tl == 38) v += sigm(al[sub][tl]);
    stf(out, (size_t)(base + a)*AOUTD + tl, v, bf);
  } else if (tl >= 40 && tl < 48){
    int n = tl - 40;
    int iv = adeg[((size_t)(base + a))*NN + n];
    int vr = ((a >> 8) << 8) + iv;
    float bl[BOUTD];
#pragma unroll
    for (int o = 0; o < BOUTD; o++)
      bl[o] = bf2f(big[(size_t)a*64 + 40 + o]) + bf2f(big[(size_t)vr*64 + 50 + o])
            + ldf(bfb, o, bf);
    float v[BOUTD];
    float m0 = fmaxf(fmaxf(bl[0],bl[1]), fmaxf(bl[2],bl[3]));
    float e0[4], s0 = 0.f;
#pragma unroll
    for (int j = 0; j < 4; j++){ e0[j] = __expf(bl[j]-m0); s0 += e0[j]; }
    float m1 = fmaxf(fmaxf(bl[6],bl[7]), fmaxf(bl[8],bl[9]));
    float e1[4], s1 = 0.f;
#pragma unroll
    for (int j = 0; j < 4; j++){ e1[j] = __expf(bl[6+j]-m1); s1 += e1[j]; }
#pragma unroll
    for (int j = 0; j < 4; j++) v[j] = e0[j]/s0;
    v[4] = sigm(bl[4]); v[5] = sigm(bl[5]);
#pragma unroll
    for (int j = 0; j < 4; j++) v[6+j] = e1[j]/s1;
    size_t op = obase + ((size_t)(base + a)*NN + n)*BOUTD;
#pragma unroll
    for (int j = 0; j < BOUTD; j++) stf(out, op + j, v[j], bf);
  }
}

extern "C" void kernel_launch(void* const* d_in, const int* in_sizes, int n_in,
                              void* d_out, int out_size, void* d_ws, size_t ws_size,
                              hipStream_t stream) {
  const int* adeg = (const int*)d_in[2];
  const void* amask = d_in[4];
  const void* molf = d_in[5];
  const void* actf = d_in[6];
  const void* afw = d_in[7];  const void* afb = d_in[8];
  const void* bfw = d_in[9];  const void* bfb = d_in[10];
  const void* alw = d_in[11]; const void* alb = d_in[12];
  const void* atw = d_in[13]; const void* atb = d_in[14];
  const void* gwih = d_in[15]; const void* gwhh = d_in[16];
  const void* gbih = d_in[17]; const void* gbhh = d_in[18];
  const void* maw = d_in[19]; const void* mab = d_in[20];
  const void* mwih = d_in[21]; const void* mwhh = d_in[22];
  const void* mbih = d_in[23]; const void* mbhh = d_in[24];

  // ---- ws layout ----
  char* w = (char*)d_ws;
  unsigned short* act  = (unsigned short*)w;  w += (size_t)BL*FDIM*2;           // 13.11 MB
  float*          mw   = (float*)w;           w += (size_t)BL*4;
  float*          pre  = (float*)w;           w += (size_t)BB*FDIM*4;
  unsigned short* wrep = (unsigned short*)w;  w += (size_t)WCHUNKS*16;          // 2.47 MB
  int*            mode = (int*)w;             w += 16;
  size_t fixed = (size_t)(w - (char*)d_ws);
  int CH = 8192;
  if (ws_size >= fixed + (size_t)32768*2800) CH = 32768;
  else if (ws_size >= fixed + (size_t)16384*2800) CH = 16384;
  unsigned short* ctx = (unsigned short*)w;   w += (size_t)CH*FDIM*2;
  unsigned short* big = (unsigned short*)w;                                     // [CH][1200]
  const int NCH = BL / CH;
  const int GY = CH/128, EWT = CH*25, EWB = EWT/256;

  k_probe<<<1, 64, 0, stream>>>((const unsigned int*)amask, mode);
  k_repack<<<(WCHUNKS + 255)/256, 256, 0, stream>>>(wrep, mwhh, maw, mwih,
      alw, atw, gwhh, gwih, afw, bfw, mode);
  k_premol<<<BB, 256, 0, stream>>>(pre, molf, maw, mab, mode);
  k_gitdot<<<BB, LL, 0, stream>>>(mw, molf, actf, mode);
  k_gitwrite<<<(BL*25 + 255)/256, 256, 0, stream>>>(act, molf, actf, mw, mode);

  // ---- mol GRU x2 ----
  for (int ts = 0; ts < 2; ts++){
    for (int c = 0; c < NCH; c++){
      int base = c*CH;
      unsigned short* Ac = act + (size_t)base*FDIM;
      k_gemm<<<dim3(5, GY), 256, 0, stream>>>(Ac, wrep + (size_t)P0*8, 640, big, 1200, 600);      // gh
      k_gemm<<<dim3(2, GY), 256, 0, stream>>>(Ac, wrep + (size_t)P1*8, 256, ctx, FDIM, FDIM);     // ctx raw
      k_ctx_ew<<<EWB, 256, 0, stream>>>(ctx, pre, base, EWT);
      k_gemm<<<dim3(5, GY), 256, 0, stream>>>(ctx, wrep + (size_t)P2*8, 640, big + 600, 1200, 600); // gi
      k_gru_ew<<<EWB, 256, 0, stream>>>(Ac, big, 600, 0, mbih, mbhh, 0ll, (ts==1), EWT, mode);
    }
  }
  // ---- 2 attention+GRU rounds ----
  for (int d = 0; d < 2; d++){
    size_t pA = (d ? P5 : P3), pB = (d ? P6 : P4);
    for (int c = 0; c < NCH; c++){
      int base = c*CH;
      unsigned short* Ac = act + (size_t)base*FDIM;
      k_gemm<<<dim3(10, GY), 256, 0, stream>>>(Ac, wrep + pA*8, 1280, big, 1200, 1200);           // S|P|Q|gh
      k_attn_ew<<<EWB, 256, 0, stream>>>(big, ctx, adeg, alb, atb, (long long)d*FDIM, base, EWT, mode);
      k_gemm<<<dim3(5, GY), 256, 0, stream>>>(ctx, wrep + pB*8, 640, big, 1200, 600);             // gi
      k_gru_ew<<<EWB, 256, 0, stream>>>(Ac, big, 0, 600, gbih, gbhh, (long long)d*600, 1, EWT, mode);
    }
  }
  // ---- decode ----
  for (int c = 0; c < NCH; c++){
    int base = c*CH;
    unsigned short* Ac = act + (size_t)base*FDIM;
    k_gemm<<<dim3(1, GY), 256, 0, stream>>>(Ac, wrep + (size_t)P7*8, 128, big, 64, 64);           // AL|U|V
    k_dec<<<CH/4, 256, 0, stream>>>(big, adeg, afb, bfb, d_out, base, mode);
  }
}

// Round 7
// 753.723 us; speedup vs baseline: 34.2712x; 1.2377x over previous
//
#include <hip/hip_runtime.h>
#include <hip/hip_bf16.h>

#define FDIM 200
#define BB   128
#define LL   256
#define NN   8
#define BL   (BB*LL)
#define AOUTD 39
#define BOUTD 10
#define KCH  28            // K chunks of 8 elems (224 = 7 MFMA steps x 32)

// chunk-major weight panels (16B chunk index bases)
#define P0 0               // mol gh  (mwhh)   Ng=640  N=600
#define P1 17920           // mol ctx (maw_n)  Ng=256  N=200
#define P2 25088           // mol gi  (mwih)   Ng=640  N=600
#define P3 43008           // rd0 S|P|Q|gh     Ng=1280 N=1200
#define P4 78848           // rd0 gi  (gwih)   Ng=640  N=600
#define P5 96768           // rd1 S|P|Q|gh     Ng=1280 N=1200
#define P6 132608          // rd1 gi           Ng=640  N=600
#define P7 150528          // dec AL|U|V       Ng=128  N=64
#define WCHUNKS 154112
#define NBIAS 4864         // f32 bias-column table entries

typedef short v8s __attribute__((ext_vector_type(8)));
typedef float v4f __attribute__((ext_vector_type(4)));

// ---------- dtype helpers (runtime bf16-vs-f32 mode for INPUT tensors) ----------
__device__ __forceinline__ float bf2f(unsigned short u){
  union { unsigned int i; float f; } v; v.i = ((unsigned int)u) << 16; return v.f;
}
__device__ __forceinline__ unsigned short f2bf(float f){
  unsigned int x = __float_as_uint(f);
  x += 0x7fffu + ((x >> 16) & 1u);   // RNE
  return (unsigned short)(x >> 16);
}
__device__ __forceinline__ float ldf(const void* p, long long i, bool bf){
  return bf ? bf2f(((const unsigned short*)p)[i]) : ((const float*)p)[i];
}
__device__ __forceinline__ void stf(void* p, size_t i, float v, bool bf){
  if (bf) ((unsigned short*)p)[i] = f2bf(v);
  else    ((float*)p)[i] = v;
}
__device__ __forceinline__ float bflo(unsigned int q){
  union { unsigned int i; float f; } v; v.i = q << 16; return v.f;
}
__device__ __forceinline__ float bfhi(unsigned int q){
  union { unsigned int i; float f; } v; v.i = q & 0xffff0000u; return v.f;
}
__device__ __forceinline__ void ld8(const unsigned short* p, float* o){
  uint4 q = *(const uint4*)p;
  o[0]=bflo(q.x); o[1]=bfhi(q.x); o[2]=bflo(q.y); o[3]=bfhi(q.y);
  o[4]=bflo(q.z); o[5]=bfhi(q.z); o[6]=bflo(q.w); o[7]=bfhi(q.w);
}
// dual-mode 8-elem vector load (16B-aligned element offset)
__device__ __forceinline__ void ld8g(const void* p, size_t i, bool bf, float* o){
  if (bf){ ld8((const unsigned short*)p + i, o); }
  else {
    const float4* q = (const float4*)((const float*)p + i);
    float4 x = q[0], y = q[1];
    o[0]=x.x; o[1]=x.y; o[2]=x.z; o[3]=x.w;
    o[4]=y.x; o[5]=y.y; o[6]=y.z; o[7]=y.w;
  }
}
__device__ __forceinline__ void st8(unsigned short* p, const float* v){
  uint4 q;
  q.x = (unsigned int)f2bf(v[0]) | ((unsigned int)f2bf(v[1]) << 16);
  q.y = (unsigned int)f2bf(v[2]) | ((unsigned int)f2bf(v[3]) << 16);
  q.z = (unsigned int)f2bf(v[4]) | ((unsigned int)f2bf(v[5]) << 16);
  q.w = (unsigned int)f2bf(v[6]) | ((unsigned int)f2bf(v[7]) << 16);
  *(uint4*)p = q;
}
// dot of a 200-long input row with f32 LDS x[200]
__device__ __forceinline__ float dotF(const void* wp, size_t off, const float* x, bool bf){
  float a0=0.f,a1=0.f,a2=0.f,a3=0.f;
  if (bf){
    const uint4* p = (const uint4*)((const unsigned short*)wp + off);
#pragma unroll
    for (int c = 0; c < FDIM/8; ++c){
      uint4 q = p[c];
      const float* xb = x + c*8;
      a0 += bflo(q.x)*xb[0]; a1 += bfhi(q.x)*xb[1];
      a2 += bflo(q.y)*xb[2]; a3 += bfhi(q.y)*xb[3];
      a0 += bflo(q.z)*xb[4]; a1 += bfhi(q.z)*xb[5];
      a2 += bflo(q.w)*xb[6]; a3 += bfhi(q.w)*xb[7];
    }
  } else {
    const float4* p = (const float4*)((const float*)wp + off);
#pragma unroll
    for (int c = 0; c < FDIM/4; ++c){
      float4 q = p[c];
      const float* xb = x + c*4;
      a0 += q.x*xb[0]; a1 += q.y*xb[1]; a2 += q.z*xb[2]; a3 += q.w*xb[3];
    }
  }
  return (a0+a1)+(a2+a3);
}
__device__ __forceinline__ float sigm(float x){ return 1.f/(1.f+__expf(-x)); }
__device__ __forceinline__ float tanh_(float x){
  float cx = fminf(fmaxf(x, -15.f), 15.f);
  float e = __expf(2.f*cx);
  return (e - 1.f)/(e + 1.f);
}
__device__ __forceinline__ float elu_(float x){ return x > 0.f ? x : __expf(x) - 1.f; }

// ---------- dtype probe: atom_mask is all 1.0 ----------
__global__ void k_probe(const unsigned int* __restrict__ amask, int* __restrict__ mode){
  if (blockIdx.x == 0 && threadIdx.x == 0)
    *mode = (amask[0] == 0x3F803F80u) ? 1 : 0;
}

// ---------- weight repack -> chunk-major bf16 panels: chunk idx = base + c*Ng + n ----------
__global__ __launch_bounds__(256) void k_repack(unsigned short* __restrict__ wrep,
    const void* mwhh, const void* maw, const void* mwih,
    const void* alw, const void* atw, const void* gwhh, const void* gwih,
    const void* afw, const void* bfw, const int* __restrict__ mode){
  const bool bf = (*mode != 0);
  int idx = blockIdx.x*256 + threadIdx.x;
  if (idx >= WCHUNKS) return;
  int pb, Ng;
  if (idx < P1)      { pb = P0; Ng = 640;  }
  else if (idx < P2) { pb = P1; Ng = 256;  }
  else if (idx < P3) { pb = P2; Ng = 640;  }
  else if (idx < P4) { pb = P3; Ng = 1280; }
  else if (idx < P5) { pb = P4; Ng = 640;  }
  else if (idx < P6) { pb = P5; Ng = 1280; }
  else if (idx < P7) { pb = P6; Ng = 640;  }
  else               { pb = P7; Ng = 128;  }
  int li = idx - pb;
  int c = li / Ng, n = li - c*Ng;
  const void* S = nullptr; long long sb = 0; int rl = 0, off = 0, row = 0, N = 0;
  if (pb == P0)      { S = mwhh; rl = 200; row = n; N = 600; }
  else if (pb == P1) { S = maw;  rl = 400; off = 200; row = n; N = 200; }
  else if (pb == P2) { S = mwih; rl = 200; row = n; N = 600; }
  else if (pb == P3 || pb == P5){
    long long d = (pb == P5) ? 1 : 0; N = 1200;
    if (n < 200)      { S = alw;  sb = d*80000;  rl = 400; off = 0;   row = n; }
    else if (n < 400) { S = alw;  sb = d*80000;  rl = 400; off = 200; row = n-200; }
    else if (n < 600) { S = atw;  sb = d*40000;  rl = 200; off = 0;   row = n-400; }
    else              { S = gwhh; sb = d*120000; rl = 200; off = 0;   row = n-600; }
  }
  else if (pb == P4 || pb == P6){
    long long d = (pb == P6) ? 1 : 0;
    S = gwih; sb = d*120000; rl = 200; row = n; N = 600;
  } else {
    N = 64;
    if (n < 39)                { S = afw; rl = 200; row = n; }
    else if (n >= 40 && n < 50){ S = bfw; rl = 400; off = 0;   row = n-40; }
    else if (n >= 50 && n < 60){ S = bfw; rl = 400; off = 200; row = n-50; }
  }
  float v[8];
#pragma unroll
  for (int j = 0; j < 8; j++){
    int k = c*8 + j;
    v[j] = (S && n < N && k < 200) ? ldf(S, sb + (long long)row*rl + off + k, bf) : 0.f;
  }
  st8(wrep + (size_t)idx*8, v);
}

// ---------- bias-column table (f32): layout
// 0 mol-gh bhh[600] | 600 mol-gi bih[600] | 1200+d*1800: alb[200]|0[200]|atb[200]|bhh_d[600]
// then bih_d[600] | 4800: afb[39]|0|bfb[10]|0[14]
__global__ __launch_bounds__(256) void k_biases(float* __restrict__ bt,
    const void* mbhh, const void* mbih, const void* alb, const void* atb,
    const void* gbhh, const void* gbih, const void* afb, const void* bfb,
    const int* __restrict__ mode){
  const bool bf = (*mode != 0);
  int e = blockIdx.x*256 + threadIdx.x;
  if (e >= NBIAS) return;
  float v = 0.f;
  if (e < 600)        v = ldf(mbhh, e, bf);
  else if (e < 1200)  v = ldf(mbih, e-600, bf);
  else if (e < 4800){
    int q = e - 1200; int d = q / 1800; q -= d*1800;
    if (q < 1200){
      if (q < 200)      v = ldf(alb, (long long)d*200 + q, bf);
      else if (q < 400) v = 0.f;
      else if (q < 600) v = ldf(atb, (long long)d*200 + q-400, bf);
      else              v = ldf(gbhh, (long long)d*600 + q-600, bf);
    } else              v = ldf(gbih, (long long)d*600 + q-1200, bf);
  } else {
    int q = e - 4800;
    if (q < 39)                 v = ldf(afb, q, bf);
    else if (q >= 40 && q < 50) v = ldf(bfb, q-40, bf);
  }
  bt[e] = v;
}

// ---------- GEMM: C[m,n] = sum_k A[m,k]*W[n,k], K=200 (padded 224) ----------
// Wc chunk-major [KCH][wNg]; 4 waves, tile 128x128; wave: 32 rows x 128 cols.
// emode: 0 plain | 1 acc+=bias[col] | 2 elu(pre_row[col]+acc), bias=pre, gbase=chunk row base
__global__ __launch_bounds__(256, 2) void k_gemm(
    const unsigned short* __restrict__ A,
    const unsigned short* __restrict__ Wc, int wNg,
    unsigned short* __restrict__ C, int ldc, int Nout,
    int emode, const float* __restrict__ bias, int gbase)
{
  __shared__ unsigned short Ws[KCH*128*8];    // 57,344 B
  int t = threadIdx.x;
  int nbase = blockIdx.x * 128;
  int mbase = blockIdx.y * 128;
  const uint4* Wg = (const uint4*)Wc;
  uint4* Wl = (uint4*)Ws;
  for (int i = t; i < KCH*128; i += 256){     // linear LDS write: conflict-free
    int c = i >> 7, n = i & 127;
    Wl[i] = Wg[(size_t)c*wNg + nbase + n];
  }
  __syncthreads();
  int wave = t >> 6, lane = t & 63;
  int quad = lane >> 4, l16 = lane & 15;
  const unsigned short* A0 = A + (size_t)(mbase + wave*32 + l16)*FDIM + quad*8;
  v4f acc[2][8];
#pragma unroll
  for (int ms = 0; ms < 2; ms++)
#pragma unroll
    for (int ns = 0; ns < 8; ns++) acc[ms][ns] = (v4f){0.f,0.f,0.f,0.f};
#pragma unroll
  for (int ks = 0; ks < 7; ks++){
    v8s a0 = *(const v8s*)(A0 + ks*32);              // k>=200 garbage x zero-W = 0
    v8s a1 = *(const v8s*)(A0 + 16*FDIM + ks*32);
    const unsigned short* Bp = Ws + ((ks*4 + quad)*128 + l16)*8;
#pragma unroll
    for (int ns = 0; ns < 8; ns++){
      v8s b = *(const v8s*)(Bp + ns*128);            // 16 lanes consecutive 16B: conflict-free
      acc[0][ns] = __builtin_amdgcn_mfma_f32_16x16x32_bf16(a0, b, acc[0][ns], 0, 0, 0);
      acc[1][ns] = __builtin_amdgcn_mfma_f32_16x16x32_bf16(a1, b, acc[1][ns], 0, 0, 0);
    }
  }
  int colb = nbase + l16;
  int rowb = mbase + wave*32 + quad*4;
  const float* pr = (emode == 2) ? (bias + (size_t)(((gbase + mbase) >> 8))*FDIM) : nullptr;
#pragma unroll
  for (int ms = 0; ms < 2; ms++){
#pragma unroll
    for (int ns = 0; ns < 8; ns++){
      int col = colb + ns*16;
      if (col < Nout){
        float badd = (emode == 1) ? bias[col] : 0.f;
        float pv   = (emode == 2) ? pr[col] : 0.f;
        unsigned short* Cp = C + (size_t)(rowb + ms*16)*ldc + col;
#pragma unroll
        for (int reg = 0; reg < 4; reg++){
          float v = acc[ms][ns][reg] + badd;
          if (emode == 2) v = elu_(pv + v);
          Cp[(size_t)reg*ldc] = f2bf(v);
        }
      }
    }
  }
}

// ---------- pre_mol[b,f] = mab[f] + dot(mol[b], maw[f, :F]) ----------
__global__ __launch_bounds__(256) void k_premol(float* __restrict__ pre,
    const void* __restrict__ molf, const void* __restrict__ maw,
    const void* __restrict__ mab, const int* __restrict__ mode){
  const bool bf = (*mode != 0);
  int b = blockIdx.x, t = threadIdx.x;
  __shared__ float mf[FDIM];
  for (int f = t; f < FDIM; f += 256) mf[f] = ldf(molf, (size_t)b*FDIM+f, bf);
  __syncthreads();
  for (int f = t; f < FDIM; f += 256)
    pre[b*FDIM+f] = ldf(mab, f, bf) + dotF(maw, (size_t)f*2*FDIM, mf, bf);
}

// ---------- mw[b,l] = softmax_l(dot(act[b,l], mol[b])) ----------
__global__ __launch_bounds__(LL) void k_gitdot(float* __restrict__ mw_out,
    const void* __restrict__ molf, const void* __restrict__ actf,
    const int* __restrict__ mode){
  const bool bf = (*mode != 0);
  int b = blockIdx.x, l = threadIdx.x;
  __shared__ float mf[FDIM];
  __shared__ float red[LL];
  for (int f = l; f < FDIM; f += LL) mf[f] = ldf(molf, (size_t)b*FDIM+f, bf);
  __syncthreads();
  float d = dotF(actf, ((size_t)b*LL + l)*FDIM, mf, bf);
  red[l] = d; __syncthreads();
  for (int s = 128; s > 0; s >>= 1){ if (l < s) red[l] = fmaxf(red[l], red[l+s]); __syncthreads(); }
  float m = red[0]; __syncthreads();
  float e = __expf(d - m);
  red[l] = e; __syncthreads();
  for (int s = 128; s > 0; s >>= 1){ if (l < s) red[l] += red[l+s]; __syncthreads(); }
  mw_out[(size_t)b*LL + l] = e / red[0];
}

// ---------- act[row,f] = mw[row]*mol[b,f] + actf[row,f] ----------
__global__ __launch_bounds__(256) void k_gitwrite(unsigned short* __restrict__ act,
    const void* __restrict__ molf, const void* __restrict__ actf,
    const float* __restrict__ mw, const int* __restrict__ mode){
  const bool bf = (*mode != 0);
  int idx = blockIdx.x*256 + threadIdx.x;
  if (idx >= BL*25) return;
  int row = idx/25, f0 = (idx - row*25)*8;
  int b = row >> 8;
  float m = mw[row];
  float mv[8], av[8], v[8];
  ld8g(molf, (size_t)b*FDIM + f0, bf, mv);
  ld8g(actf, (size_t)row*FDIM + f0, bf, av);
#pragma unroll
  for (int j = 0; j < 8; j++) v[j] = m*mv[j] + av[j];
  st8(act + (size_t)row*FDIM + f0, v);
}

// ---------- GRU elementwise, 8-wide; biases pre-folded into gates ----------
__global__ __launch_bounds__(256) void k_gru_ew(unsigned short* __restrict__ act,
    const unsigned short* __restrict__ big, int gio, int gho,
    int dorelu, int total){
  int idx = blockIdx.x*256 + threadIdx.x;
  if (idx >= total) return;
  int row = idx/25, f0 = (idx - row*25)*8;
  size_t g = (size_t)row*1200;
  float gr[8], gz[8], gn[8], hr[8], hz[8], hn_[8], h[8], o[8];
  ld8(big + g + gio + f0,       gr);
  ld8(big + g + gio + 200 + f0, gz);
  ld8(big + g + gio + 400 + f0, gn);
  ld8(big + g + gho + f0,       hr);
  ld8(big + g + gho + 200 + f0, hz);
  ld8(big + g + gho + 400 + f0, hn_);
  ld8(act + (size_t)row*FDIM + f0, h);
#pragma unroll
  for (int j = 0; j < 8; j++){
    float r = sigm(gr[j] + hr[j]);
    float z = sigm(gz[j] + hz[j]);
    float n = tanh_(gn[j] + r*hn_[j]);
    float hn = (1.f - z)*n + z*h[j];
    o[j] = dorelu ? fmaxf(hn, 0.f) : hn;
  }
  st8(act + (size_t)row*FDIM + f0, o);
}

// ---------- attention elementwise, 8-wide: big[S'|P|Q'] -> ctx (biases folded) ----------
__global__ __launch_bounds__(256) void k_attn_ew(const unsigned short* __restrict__ big,
    unsigned short* __restrict__ ctx, const int* __restrict__ adeg,
    int base, int total){
  int idx = blockIdx.x*256 + threadIdx.x;
  if (idx >= total) return;
  int a = idx/25, f0 = (idx - a*25)*8;
  int mb = (a >> 8) << 8;
  float s0[8];
  ld8(big + (size_t)a*1200 + f0, s0);
  int4 d0 = *(const int4*)(adeg + (size_t)(base + a)*NN);
  int4 d1 = *(const int4*)(adeg + (size_t)(base + a)*NN + 4);
  int iv[NN] = {d0.x, d0.y, d0.z, d0.w, d1.x, d1.y, d1.z, d1.w};
  int nid[NN]; float nmul[NN], nadd[NN];
#pragma unroll
  for (int n = 0; n < NN; n++){
    nid[n] = mb + iv[n];
    bool pad = (iv[n] == LL-1);
    nmul[n] = pad ? 0.f : 1.f;
    nadd[n] = pad ? -9e8f : 0.f;
  }
  float e[NN][8], mx[8];
#pragma unroll
  for (int j = 0; j < 8; j++) mx[j] = -1e30f;
#pragma unroll
  for (int n = 0; n < NN; n++){
    float p[8];
    ld8(big + (size_t)nid[n]*1200 + 200 + f0, p);
#pragma unroll
    for (int j = 0; j < 8; j++){
      float s = s0[j] + p[j];
      s = s > 0.f ? s : 0.01f*s;
      s += nadd[n];
      e[n][j] = s;
      mx[j] = fmaxf(mx[j], s);
    }
  }
  float sum[8] = {0,0,0,0,0,0,0,0};
#pragma unroll
  for (int n = 0; n < NN; n++)
#pragma unroll
    for (int j = 0; j < 8; j++){ e[n][j] = __expf(e[n][j] - mx[j]); sum[j] += e[n][j]; }
  float acc[8] = {0,0,0,0,0,0,0,0};
#pragma unroll
  for (int n = 0; n < NN; n++){
    float q[8];
    ld8(big + (size_t)nid[n]*1200 + 400 + f0, q);
#pragma unroll
    for (int j = 0; j < 8; j++) acc[j] += e[n][j]*nmul[n]*q[j];
  }
  float o[8];
#pragma unroll
  for (int j = 0; j < 8; j++) o[j] = elu_(acc[j]/sum[j]);
  st8(ctx + (size_t)a*FDIM + f0, o);
}

// ---------- merged decode: 4 atoms/block (biases pre-folded into big) ----------
__global__ __launch_bounds__(256) void k_dec(const unsigned short* __restrict__ big,
    const int* __restrict__ adeg, void* __restrict__ out, int base,
    const int* __restrict__ mode){
  const bool bf = (*mode != 0);
  const size_t obase = (size_t)BL*AOUTD;
  int sub = threadIdx.x >> 6, tl = threadIdx.x & 63;
  int a = blockIdx.x*4 + sub;
  __shared__ float al[4][40];
  __shared__ float sm[4][4], ss[4][4];
  const int lo[4] = {0,16,24,31}, hi[4] = {16,22,30,36};
  if (tl < AOUTD) al[sub][tl] = bf2f(big[(size_t)a*64 + tl]);
  __syncthreads();
  if (tl < 4){
    float m = -1e30f;
    for (int k = lo[tl]; k < hi[tl]; k++) m = fmaxf(m, al[sub][k]);
    float s = 0.f;
    for (int k = lo[tl]; k < hi[tl]; k++) s += __expf(al[sub][k]-m);
    sm[sub][tl] = m; ss[sub][tl] = s;
  }
  __syncthreads();
  if (tl < AOUTD){
    float v = 0.f;
#pragma unroll
    for (int g = 0; g < 4; g++)
      if (tl >= lo[g] && tl < hi[g]) v += __expf(al[sub][tl]-sm[sub][g])/ss[sub][g];
    if (tl == 24) v += fmaxf(al[sub][24], 0.f);
    if (tl == 30 || tl == 36 || tl == 37 || tl == 38) v += sigm(al[sub][tl]);
    stf(out, (size_t)(base + a)*AOUTD + tl, v, bf);
  } else if (tl >= 40 && tl < 48){
    int n = tl - 40;
    int iv = adeg[((size_t)(base + a))*NN + n];
    int vr = ((a >> 8) << 8) + iv;
    float bl[BOUTD];
#pragma unroll
    for (int o = 0; o < BOUTD; o++)
      bl[o] = bf2f(big[(size_t)a*64 + 40 + o]) + bf2f(big[(size_t)vr*64 + 50 + o]);
    float v[BOUTD];
    float m0 = fmaxf(fmaxf(bl[0],bl[1]), fmaxf(bl[2],bl[3]));
    float e0[4], s0 = 0.f;
#pragma unroll
    for (int j = 0; j < 4; j++){ e0[j] = __expf(bl[j]-m0); s0 += e0[j]; }
    float m1 = fmaxf(fmaxf(bl[6],bl[7]), fmaxf(bl[8],bl[9]));
    float e1[4], s1 = 0.f;
#pragma unroll
    for (int j = 0; j < 4; j++){ e1[j] = __expf(bl[6+j]-m1); s1 += e1[j]; }
#pragma unroll
    for (int j = 0; j < 4; j++) v[j] = e0[j]/s0;
    v[4] = sigm(bl[4]); v[5] = sigm(bl[5]);
#pragma unroll
    for (int j = 0; j < 4; j++) v[6+j] = e1[j]/s1;
    size_t op = obase + ((size_t)(base + a)*NN + n)*BOUTD;
#pragma unroll
    for (int j = 0; j < BOUTD; j++) stf(out, op + j, v[j], bf);
  }
}

extern "C" void kernel_launch(void* const* d_in, const int* in_sizes, int n_in,
                              void* d_out, int out_size, void* d_ws, size_t ws_size,
                              hipStream_t stream) {
  const int* adeg = (const int*)d_in[2];
  const void* amask = d_in[4];
  const void* molf = d_in[5];
  const void* actf = d_in[6];
  const void* afw = d_in[7];  const void* afb = d_in[8];
  const void* bfw = d_in[9];  const void* bfb = d_in[10];
  const void* alw = d_in[11]; const void* alb = d_in[12];
  const void* atw = d_in[13]; const void* atb = d_in[14];
  const void* gwih = d_in[15]; const void* gwhh = d_in[16];
  const void* gbih = d_in[17]; const void* gbhh = d_in[18];
  const void* maw = d_in[19]; const void* mab = d_in[20];
  const void* mwih = d_in[21]; const void* mwhh = d_in[22];
  const void* mbih = d_in[23]; const void* mbhh = d_in[24];

  // ---- ws layout ----
  char* w = (char*)d_ws;
  unsigned short* act  = (unsigned short*)w;  w += (size_t)BL*FDIM*2;           // 13.11 MB
  float*          mw   = (float*)w;           w += (size_t)BL*4;
  float*          pre  = (float*)w;           w += (size_t)BB*FDIM*4;
  unsigned short* wrep = (unsigned short*)w;  w += (size_t)WCHUNKS*16;          // 2.47 MB
  float*          bt   = (float*)w;           w += (size_t)NBIAS*4;
  int*            mode = (int*)w;             w += 16;
  size_t fixed = (size_t)(w - (char*)d_ws);
  int CH = 8192;
  if (ws_size >= fixed + (size_t)32768*2800) CH = 32768;
  else if (ws_size >= fixed + (size_t)16384*2800) CH = 16384;
  unsigned short* ctx = (unsigned short*)w;   w += (size_t)CH*FDIM*2;
  unsigned short* big = (unsigned short*)w;                                     // [CH][1200]
  const int NCH = BL / CH;
  const int GY = CH/128, EWT = CH*25, EWB = EWT/256;

  k_probe<<<1, 64, 0, stream>>>((const unsigned int*)amask, mode);
  k_repack<<<(WCHUNKS + 255)/256, 256, 0, stream>>>(wrep, mwhh, maw, mwih,
      alw, atw, gwhh, gwih, afw, bfw, mode);
  k_biases<<<(NBIAS + 255)/256, 256, 0, stream>>>(bt, mbhh, mbih, alb, atb,
      gbhh, gbih, afb, bfb, mode);
  k_premol<<<BB, 256, 0, stream>>>(pre, molf, maw, mab, mode);
  k_gitdot<<<BB, LL, 0, stream>>>(mw, molf, actf, mode);
  k_gitwrite<<<(BL*25 + 255)/256, 256, 0, stream>>>(act, molf, actf, mw, mode);

  // ---- mol GRU x2 ----
  for (int ts = 0; ts < 2; ts++){
    for (int c = 0; c < NCH; c++){
      int base = c*CH;
      unsigned short* Ac = act + (size_t)base*FDIM;
      k_gemm<<<dim3(5, GY), 256, 0, stream>>>(Ac, wrep + (size_t)P0*8, 640,
          big, 1200, 600, 1, bt + 0, 0);                                        // gh (+bhh)
      k_gemm<<<dim3(2, GY), 256, 0, stream>>>(Ac, wrep + (size_t)P1*8, 256,
          ctx, FDIM, FDIM, 2, pre, base);                                       // ctx = elu(pre+.)
      k_gemm<<<dim3(5, GY), 256, 0, stream>>>(ctx, wrep + (size_t)P2*8, 640,
          big + 600, 1200, 600, 1, bt + 600, 0);                                // gi (+bih)
      k_gru_ew<<<EWB, 256, 0, stream>>>(Ac, big, 600, 0, (ts==1), EWT);
    }
  }
  // ---- 2 attention+GRU rounds ----
  for (int d = 0; d < 2; d++){
    size_t pA = (d ? P5 : P3), pB = (d ? P6 : P4);
    float* btA = bt + 1200 + d*1800;
    float* btB = bt + 2400 + d*1800;
    for (int c = 0; c < NCH; c++){
      int base = c*CH;
      unsigned short* Ac = act + (size_t)base*FDIM;
      k_gemm<<<dim3(10, GY), 256, 0, stream>>>(Ac, wrep + pA*8, 1280,
          big, 1200, 1200, 1, btA, 0);                                          // S'|P|Q'|gh'
      k_attn_ew<<<EWB, 256, 0, stream>>>(big, ctx, adeg, base, EWT);
      k_gemm<<<dim3(5, GY), 256, 0, stream>>>(ctx, wrep + pB*8, 640,
          big, 1200, 600, 1, btB, 0);                                           // gi'
      k_gru_ew<<<EWB, 256, 0, stream>>>(Ac, big, 0, 600, 1, EWT);
    }
  }
  // ---- decode ----
  for (int c = 0; c < NCH; c++){
    int base = c*CH;
    unsigned short* Ac = act + (size_t)base*FDIM;
    k_gemm<<<dim3(1, GY), 256, 0, stream>>>(Ac, wrep + (size_t)P7*8, 128,
        big, 64, 64, 1, bt + 4800, 0);                                          // AL|U|V (+afb,bfb)
    k_dec<<<CH/4, 256, 0, stream>>>(big, adeg, d_out, base, mode);
  }
}